// Round 2
// baseline (337.330 us; speedup 1.0000x reference)
//
#include <hip/hip_runtime.h>
#include <math.h>

typedef unsigned short u16;
typedef unsigned int u32;
typedef __bf16 bf16x8_t __attribute__((ext_vector_type(8)));
typedef float f32x4_t __attribute__((ext_vector_type(4)));

__device__ __forceinline__ u16 f2bf(float f) {
  __bf16 b = (__bf16)f;
  return __builtin_bit_cast(u16, b);
}

__device__ __forceinline__ void gld16(const void* g, void* l) {
  __builtin_amdgcn_global_load_lds(
      (const __attribute__((address_space(1))) void*)g,
      (__attribute__((address_space(3))) void*)l, 16, 0, 0);
}

// ---------------------------------------------------------------------------
// cast fp32 -> bf16 (weights)
__global__ __launch_bounds__(256) void cast_kernel(const float* __restrict__ src,
                                                   u16* __restrict__ dst, int n) {
  int i = (blockIdx.x * 256 + threadIdx.x) * 4;
  if (i < n) {
    float4 v = *(const float4*)(src + i);
    uint2 o;
    o.x = (u32)f2bf(v.x) | ((u32)f2bf(v.y) << 16);
    o.y = (u32)f2bf(v.z) | ((u32)f2bf(v.w) << 16);
    *(uint2*)(dst + i) = o;
  }
}

// ---------------------------------------------------------------------------
// b2ob[c] = b2[c] + sum_i grn_b[i]*w2[c][i]
__global__ __launch_bounds__(64) void b2ob_kernel(const float* __restrict__ w2,
                                                  const float* __restrict__ grn_b,
                                                  const float* __restrict__ b2,
                                                  float* __restrict__ out) {
  int c = blockIdx.x;
  int l = threadIdx.x;
  float p = 0.f;
  for (int i = l; i < 1536; i += 64) p += grn_b[i] * w2[(size_t)c * 1536 + i];
  #pragma unroll
  for (int s = 32; s; s >>= 1) p += __shfl_xor(p, s);
  if (l == 0) out[c] = b2[c] + p;
}

// ---------------------------------------------------------------------------
// depthwise conv (K=7, pad 3) + LayerNorm over C, output bf16 [B*T][512]
__global__ __launch_bounds__(256) void conv_ln_kernel(const float* __restrict__ X,
                                                      const float* __restrict__ Wd,
                                                      const float* __restrict__ bd,
                                                      const float* __restrict__ lng,
                                                      const float* __restrict__ lnb,
                                                      u16* __restrict__ Y) {
  __shared__ float red0[256];
  __shared__ float red1[256];
  __shared__ float mu_s[16], rs_s[16];
  __shared__ __align__(16) u16 stage[16 * 520];

  const int tid = threadIdx.x;
  const int tl = tid & 15;        // local t
  const int cg = tid >> 4;        // channel group (32 c each)
  const int b = blockIdx.y;
  const int t0 = blockIdx.x * 16;
  const int t = t0 + tl;

  const float* xb = X + (size_t)b * 512 * 2048;
  float yv[32];
  float sum = 0.f, sq = 0.f;
  #pragma unroll
  for (int j = 0; j < 32; ++j) {
    int c = cg * 32 + j;
    const float* xr = xb + (size_t)c * 2048;
    const float* wr = Wd + c * 7;
    float a = bd[c];
    #pragma unroll
    for (int k = 0; k < 7; ++k) {
      int tt = t + k - 3;
      if (tt >= 0 && tt < 2048) a += xr[tt] * wr[k];
    }
    yv[j] = a;
    sum += a;
    sq += a * a;
  }
  red0[tid] = sum;
  red1[tid] = sq;
  __syncthreads();
  if (tid < 16) {
    float s = 0.f, q = 0.f;
    #pragma unroll
    for (int g = 0; g < 16; ++g) { s += red0[g * 16 + tid]; q += red1[g * 16 + tid]; }
    float mu = s * (1.f / 512.f);
    float var = q * (1.f / 512.f) - mu * mu;
    mu_s[tid] = mu;
    rs_s[tid] = rsqrtf(var + 1e-6f);
  }
  __syncthreads();
  float mu = mu_s[tl], rs = rs_s[tl];
  #pragma unroll
  for (int j = 0; j < 32; ++j) {
    int c = cg * 32 + j;
    float v = (yv[j] - mu) * rs * lng[c] + lnb[c];
    stage[tl * 520 + c] = f2bf(v);
  }
  __syncthreads();
  // coalesced write: 16 rows x 512 bf16
  #pragma unroll
  for (int it = 0; it < 4; ++it) {
    int idx = it * 256 + tid;   // 0..1023
    int row = idx >> 6;         // 0..15
    int cb = idx & 63;          // 0..63 (8 bf16 chunks)
    uint4 v = *(const uint4*)(stage + row * 520 + cb * 8);
    *(uint4*)(Y + (size_t)(b * 2048 + t0 + row) * 512 + cb * 8) = v;
  }
}

// ---------------------------------------------------------------------------
// GEMM1: h[m][n] = gelu( y_ln[m][:] . w1[n][:] + b1[n] ), M=32768 K=512 N=1536
// also accumulates gsum[b][n] += sum_rows gelu^2 (for GRN)
__global__ __launch_bounds__(256, 2) void gemm1_kernel(const u16* __restrict__ A,
                                                       const u16* __restrict__ B,
                                                       const float* __restrict__ b1,
                                                       u16* __restrict__ H,
                                                       float* __restrict__ gsum) {
  __shared__ __align__(16) u16 smem[128 * 136];   // tiles: 2x 128*64; epilogue stage 128x136
  u16* lA = smem;
  u16* lB = smem + 128 * 64;

  const int tid = threadIdx.x;
  const int w = tid >> 6;
  const int l = tid & 63;
  const int m0 = blockIdx.x * 128;
  const int n0 = blockIdx.y * 128;
  const int bidx = m0 >> 11;
  const int wm = w >> 1, wn = w & 1;

  f32x4_t acc[4][4];
  #pragma unroll
  for (int i = 0; i < 4; ++i)
    #pragma unroll
    for (int j = 0; j < 4; ++j) {
      f32x4_t z = {0.f, 0.f, 0.f, 0.f};
      acc[i][j] = z;
    }

  const int rowInc = w * 8 + (l >> 3);
  const int colE = (l & 7) * 8;
  const u16* Abase = A + (size_t)(m0 + rowInc) * 512 + colE;
  const u16* Bbase = B + (size_t)(n0 + rowInc) * 512 + colE;
  const int ldsOff = w * 512;   // elems; + c*2048; HW adds lane*16B

  for (int kt = 0; kt < 512; kt += 64) {
    #pragma unroll
    for (int c = 0; c < 4; ++c) {
      gld16(Abase + (size_t)(c * 32) * 512 + kt, lA + c * 2048 + ldsOff);
      gld16(Bbase + (size_t)(c * 32) * 512 + kt, lB + c * 2048 + ldsOff);
    }
    __syncthreads();
    #pragma unroll
    for (int kk = 0; kk < 2; ++kk) {
      bf16x8_t af[4], bfr[4];
      #pragma unroll
      for (int f = 0; f < 4; ++f) {
        int arow = wm * 64 + f * 16 + (l & 15);
        af[f] = *(const bf16x8_t*)(lA + arow * 64 + kk * 32 + (l >> 4) * 8);
        int brow = wn * 64 + f * 16 + (l & 15);
        bfr[f] = *(const bf16x8_t*)(lB + brow * 64 + kk * 32 + (l >> 4) * 8);
      }
      #pragma unroll
      for (int i = 0; i < 4; ++i)
        #pragma unroll
        for (int j = 0; j < 4; ++j)
          acc[i][j] = __builtin_amdgcn_mfma_f32_16x16x32_bf16(af[i], bfr[j], acc[i][j], 0, 0, 0);
    }
    __syncthreads();
  }

  // epilogue: bias + exact GELU, stage bf16 to LDS, atomic sumsq per column
  const int lrow = (l >> 4) * 4;
  const int lcol = l & 15;
  float bj[4];
  #pragma unroll
  for (int j = 0; j < 4; ++j) bj[j] = b1[n0 + wn * 64 + j * 16 + lcol];

  float ss[4] = {0.f, 0.f, 0.f, 0.f};
  #pragma unroll
  for (int i = 0; i < 4; ++i) {
    int row = wm * 64 + i * 16 + lrow;
    #pragma unroll
    for (int j = 0; j < 4; ++j) {
      int col = wn * 64 + j * 16 + lcol;
      #pragma unroll
      for (int r = 0; r < 4; ++r) {
        float v = acc[i][j][r] + bj[j];
        float g = 0.5f * v * (1.0f + erff(v * 0.70710678118654752f));
        ss[j] += g * g;
        smem[(row + r) * 136 + col] = f2bf(g);
      }
    }
  }
  #pragma unroll
  for (int j = 0; j < 4; ++j) {
    float v = ss[j];
    v += __shfl_xor(v, 16);
    v += __shfl_xor(v, 32);
    if ((l >> 4) == 0)
      atomicAdd(&gsum[bidx * 1536 + n0 + wn * 64 + j * 16 + lcol], v);
  }
  __syncthreads();
  #pragma unroll
  for (int it = 0; it < 8; ++it) {
    int idx = it * 256 + tid;   // 0..2047
    int row = idx >> 4;         // 0..127
    int cb = idx & 15;
    uint4 v = *(const uint4*)(smem + row * 136 + cb * 8);
    *(uint4*)(H + (size_t)(m0 + row) * 1536 + n0 + cb * 8) = v;
  }
}

// ---------------------------------------------------------------------------
// GRN scale: s[b][i] = 1 + grn_g[i] * gx / (mean_i(gx) + 1e-6), gx = sqrt(gsum)
__global__ __launch_bounds__(256) void grn_kernel(const float* __restrict__ gsum,
                                                  const float* __restrict__ grn_g,
                                                  float* __restrict__ svec) {
  __shared__ float red[256];
  int b = blockIdx.x, tid = threadIdx.x;
  float gx[6];
  float part = 0.f;
  #pragma unroll
  for (int it = 0; it < 6; ++it) {
    int i = it * 256 + tid;
    gx[it] = sqrtf(gsum[b * 1536 + i]);
    part += gx[it];
  }
  red[tid] = part;
  __syncthreads();
  for (int s = 128; s; s >>= 1) {
    if (tid < s) red[tid] += red[tid + s];
    __syncthreads();
  }
  float inv = 1.0f / (red[0] * (1.f / 1536.f) + 1e-6f);
  #pragma unroll
  for (int it = 0; it < 6; ++it) {
    int i = it * 256 + tid;
    svec[b * 1536 + i] = 1.0f + grn_g[i] * gx[it] * inv;
  }
}

// ---------------------------------------------------------------------------
// GEMM2: out[b][c][t] = x[b][c][t] + (h[m][:] * s[b][:]) . w2[c][:] + b2ob[c]
// M=32768 K=1536 N=512.  A reg-staged (scale applied), B via global_load_lds.
__global__ __launch_bounds__(256, 2) void gemm2_kernel(const u16* __restrict__ Hs,
                                                       const u16* __restrict__ B,
                                                       const float* __restrict__ svec,
                                                       const float* __restrict__ b2ob,
                                                       const float* __restrict__ X,
                                                       float* __restrict__ Out) {
  __shared__ __align__(16) u16 smem[16512];  // tiles 2x8192 u16 (32KB); ostage 64x129 f32 (33024B)
  u16* lA = smem;
  u16* lB = smem + 8192;

  const int tid = threadIdx.x;
  const int w = tid >> 6;
  const int l = tid & 63;
  const int m0 = blockIdx.x * 128;
  const int n0 = blockIdx.y * 128;
  const int bidx = m0 >> 11;
  const int t0 = m0 & 2047;
  const int wm = w >> 1, wn = w & 1;

  f32x4_t acc[4][4];
  #pragma unroll
  for (int i = 0; i < 4; ++i)
    #pragma unroll
    for (int j = 0; j < 4; ++j) {
      f32x4_t z = {0.f, 0.f, 0.f, 0.f};
      acc[i][j] = z;
    }

  const int rowInc = w * 8 + (l >> 3);
  const int colE = (l & 7) * 8;
  const u16* Abase = Hs + (size_t)(m0 + rowInc) * 1536 + colE;
  const u16* Bbase = B + (size_t)(n0 + rowInc) * 1536 + colE;
  const float* sb = svec + bidx * 1536 + colE;
  const int ldsOff = w * 512;

  for (int kt = 0; kt < 1536; kt += 64) {
    // B tile: async direct-to-LDS
    #pragma unroll
    for (int c = 0; c < 4; ++c)
      gld16(Bbase + (size_t)(c * 32) * 1536 + kt, lB + c * 2048 + ldsOff);
    // A tile: reg-staged with GRN scale folded in
    float4 s0 = *(const float4*)(sb + kt);
    float4 s1 = *(const float4*)(sb + kt + 4);
    float sv[8] = {s0.x, s0.y, s0.z, s0.w, s1.x, s1.y, s1.z, s1.w};
    #pragma unroll
    for (int c = 0; c < 4; ++c) {
      bf16x8_t hv = *(const bf16x8_t*)(Abase + (size_t)(c * 32) * 1536 + kt);
      bf16x8_t ov;
      #pragma unroll
      for (int e = 0; e < 8; ++e) ov[e] = (__bf16)((float)hv[e] * sv[e]);
      *(bf16x8_t*)(lA + c * 2048 + ldsOff + l * 8) = ov;
    }
    __syncthreads();
    #pragma unroll
    for (int kk = 0; kk < 2; ++kk) {
      bf16x8_t af[4], bfr[4];
      #pragma unroll
      for (int f = 0; f < 4; ++f) {
        int arow = wm * 64 + f * 16 + (l & 15);
        af[f] = *(const bf16x8_t*)(lA + arow * 64 + kk * 32 + (l >> 4) * 8);
        int brow = wn * 64 + f * 16 + (l & 15);
        bfr[f] = *(const bf16x8_t*)(lB + brow * 64 + kk * 32 + (l >> 4) * 8);
      }
      #pragma unroll
      for (int i = 0; i < 4; ++i)
        #pragma unroll
        for (int j = 0; j < 4; ++j)
          acc[i][j] = __builtin_amdgcn_mfma_f32_16x16x32_bf16(af[i], bfr[j], acc[i][j], 0, 0, 0);
    }
    __syncthreads();
  }

  // epilogue: transpose through LDS (fp32, stride 129 -> conflict-free col read),
  // add b2ob + residual, write out[b][c][t]
  float* ostage = (float*)smem;
  #pragma unroll
  for (int half = 0; half < 2; ++half) {
    if (wm == half) {
      #pragma unroll
      for (int i = 0; i < 4; ++i) {
        int lr = i * 16 + (l >> 4) * 4;   // 0..63 within half
        #pragma unroll
        for (int j = 0; j < 4; ++j) {
          int col = wn * 64 + j * 16 + (l & 15);
          #pragma unroll
          for (int r = 0; r < 4; ++r) ostage[(lr + r) * 129 + col] = acc[i][j][r];
        }
      }
    }
    __syncthreads();
    #pragma unroll
    for (int it = 0; it < 32; ++it) {
      int cl = it * 4 + w;      // 0..127
      int c = n0 + cl;
      float v = ostage[l * 129 + cl];
      size_t oidx = ((size_t)bidx * 512 + c) * 2048 + t0 + half * 64 + l;
      Out[oidx] = v + b2ob[c] + X[oidx];
    }
    __syncthreads();
  }
}

// ---------------------------------------------------------------------------
extern "C" void kernel_launch(void* const* d_in, const int* in_sizes, int n_in,
                              void* d_out, int out_size, void* d_ws, size_t ws_size,
                              hipStream_t stream) {
  const float* x     = (const float*)d_in[0];
  const float* dw_w  = (const float*)d_in[1];
  const float* dw_b  = (const float*)d_in[2];
  const float* ln_g  = (const float*)d_in[3];
  const float* ln_b  = (const float*)d_in[4];
  const float* w1    = (const float*)d_in[5];
  const float* b1    = (const float*)d_in[6];
  const float* grn_g = (const float*)d_in[7];
  const float* grn_b = (const float*)d_in[8];
  const float* w2    = (const float*)d_in[9];
  const float* b2    = (const float*)d_in[10];
  float* out = (float*)d_out;

  // workspace layout (all 16B aligned)
  u16* y_ln = (u16*)d_ws;                             // 32768*512
  u16* h    = y_ln + (size_t)32768 * 512;             // 32768*1536
  u16* w1b  = h + (size_t)32768 * 1536;               // 1536*512
  u16* w2b  = w1b + (size_t)1536 * 512;               // 512*1536
  float* gsum = (float*)(w2b + (size_t)512 * 1536);   // 16*1536
  float* svec = gsum + 16 * 1536;                     // 16*1536
  float* b2ob = svec + 16 * 1536;                     // 512

  hipMemsetAsync(gsum, 0, 16 * 1536 * sizeof(float), stream);
  cast_kernel<<<768, 256, 0, stream>>>(w1, w1b, 1536 * 512);
  cast_kernel<<<768, 256, 0, stream>>>(w2, w2b, 512 * 1536);
  b2ob_kernel<<<512, 64, 0, stream>>>(w2, grn_b, b2, b2ob);
  conv_ln_kernel<<<dim3(128, 16), 256, 0, stream>>>(x, dw_w, dw_b, ln_g, ln_b, y_ln);
  gemm1_kernel<<<dim3(256, 12), 256, 0, stream>>>(y_ln, w1b, b1, h, gsum);
  grn_kernel<<<16, 256, 0, stream>>>(gsum, grn_g, svec);
  gemm2_kernel<<<dim3(256, 4), 256, 0, stream>>>(h, w2b, svec, b2ob, x, out);
}

// Round 3
// 335.743 us; speedup vs baseline: 1.0047x; 1.0047x over previous
//
#include <hip/hip_runtime.h>
#include <math.h>

typedef unsigned short u16;
typedef unsigned int u32;
typedef __bf16 bf16x8_t __attribute__((ext_vector_type(8)));
typedef float f32x4_t __attribute__((ext_vector_type(4)));

__device__ __forceinline__ u16 f2bf(float f) {
  __bf16 b = (__bf16)f;
  return __builtin_bit_cast(u16, b);
}

__device__ __forceinline__ void gld16(const void* g, void* l) {
  __builtin_amdgcn_global_load_lds(
      (const __attribute__((address_space(1))) void*)g,
      (__attribute__((address_space(3))) void*)l, 16, 0, 0);
}

// ---------------------------------------------------------------------------
// cast fp32 -> bf16 (weights)
__global__ __launch_bounds__(256) void cast_kernel(const float* __restrict__ src,
                                                   u16* __restrict__ dst, int n) {
  int i = (blockIdx.x * 256 + threadIdx.x) * 4;
  if (i < n) {
    float4 v = *(const float4*)(src + i);
    uint2 o;
    o.x = (u32)f2bf(v.x) | ((u32)f2bf(v.y) << 16);
    o.y = (u32)f2bf(v.z) | ((u32)f2bf(v.w) << 16);
    *(uint2*)(dst + i) = o;
  }
}

// ---------------------------------------------------------------------------
// b2ob[c] = b2[c] + sum_i grn_b[i]*w2[c][i]
__global__ __launch_bounds__(64) void b2ob_kernel(const float* __restrict__ w2,
                                                  const float* __restrict__ grn_b,
                                                  const float* __restrict__ b2,
                                                  float* __restrict__ out) {
  int c = blockIdx.x;
  int l = threadIdx.x;
  float p = 0.f;
  for (int i = l; i < 1536; i += 64) p += grn_b[i] * w2[(size_t)c * 1536 + i];
  #pragma unroll
  for (int s = 32; s; s >>= 1) p += __shfl_xor(p, s);
  if (l == 0) out[c] = b2[c] + p;
}

// ---------------------------------------------------------------------------
// depthwise conv (K=7, pad 3) + LayerNorm over C, output bf16 [B*T][512]
__global__ __launch_bounds__(256) void conv_ln_kernel(const float* __restrict__ X,
                                                      const float* __restrict__ Wd,
                                                      const float* __restrict__ bd,
                                                      const float* __restrict__ lng,
                                                      const float* __restrict__ lnb,
                                                      u16* __restrict__ Y) {
  __shared__ float red0[256];
  __shared__ float red1[256];
  __shared__ float mu_s[16], rs_s[16];
  __shared__ __align__(16) u16 stage[16 * 520];

  const int tid = threadIdx.x;
  const int tl = tid & 15;        // local t
  const int cg = tid >> 4;        // channel group (32 c each)
  const int b = blockIdx.y;
  const int t0 = blockIdx.x * 16;
  const int t = t0 + tl;

  const float* xb = X + (size_t)b * 512 * 2048;
  float yv[32];
  float sum = 0.f, sq = 0.f;
  #pragma unroll
  for (int j = 0; j < 32; ++j) {
    int c = cg * 32 + j;
    const float* xr = xb + (size_t)c * 2048;
    const float* wr = Wd + c * 7;
    float a = bd[c];
    #pragma unroll
    for (int k = 0; k < 7; ++k) {
      int tt = t + k - 3;
      if (tt >= 0 && tt < 2048) a += xr[tt] * wr[k];
    }
    yv[j] = a;
    sum += a;
    sq += a * a;
  }
  red0[tid] = sum;
  red1[tid] = sq;
  __syncthreads();
  if (tid < 16) {
    float s = 0.f, q = 0.f;
    #pragma unroll
    for (int g = 0; g < 16; ++g) { s += red0[g * 16 + tid]; q += red1[g * 16 + tid]; }
    float mu = s * (1.f / 512.f);
    float var = q * (1.f / 512.f) - mu * mu;
    mu_s[tid] = mu;
    rs_s[tid] = rsqrtf(var + 1e-6f);
  }
  __syncthreads();
  float mu = mu_s[tl], rs = rs_s[tl];
  #pragma unroll
  for (int j = 0; j < 32; ++j) {
    int c = cg * 32 + j;
    float v = (yv[j] - mu) * rs * lng[c] + lnb[c];
    stage[tl * 520 + c] = f2bf(v);
  }
  __syncthreads();
  // coalesced write: 16 rows x 512 bf16
  #pragma unroll
  for (int it = 0; it < 4; ++it) {
    int idx = it * 256 + tid;   // 0..1023
    int row = idx >> 6;         // 0..15
    int cb = idx & 63;          // 0..63 (8 bf16 chunks)
    uint4 v = *(const uint4*)(stage + row * 520 + cb * 8);
    *(uint4*)(Y + (size_t)(b * 2048 + t0 + row) * 512 + cb * 8) = v;
  }
}

// ---------------------------------------------------------------------------
// GEMM1: h[m][n] = gelu( y_ln[m][:] . w1[n][:] + b1[n] ), M=32768 K=512 N=1536
// also accumulates gsum[b][n] += sum_rows gelu^2 (for GRN)
__global__ __launch_bounds__(256, 2) void gemm1_kernel(const u16* __restrict__ A,
                                                       const u16* __restrict__ B,
                                                       const float* __restrict__ b1,
                                                       u16* __restrict__ H,
                                                       float* __restrict__ gsum) {
  __shared__ __align__(16) u16 smem[128 * 136];   // tiles: 2x 128*64; epilogue stage 128x136
  u16* lA = smem;
  u16* lB = smem + 128 * 64;

  const int tid = threadIdx.x;
  const int w = tid >> 6;
  const int l = tid & 63;
  const int m0 = blockIdx.x * 128;
  const int n0 = blockIdx.y * 128;
  const int bidx = m0 >> 11;
  const int wm = w >> 1, wn = w & 1;

  f32x4_t acc[4][4];
  #pragma unroll
  for (int i = 0; i < 4; ++i)
    #pragma unroll
    for (int j = 0; j < 4; ++j) {
      f32x4_t z = {0.f, 0.f, 0.f, 0.f};
      acc[i][j] = z;
    }

  const int rowInc = w * 8 + (l >> 3);
  const int colE = (l & 7) * 8;
  const u16* Abase = A + (size_t)(m0 + rowInc) * 512 + colE;
  const u16* Bbase = B + (size_t)(n0 + rowInc) * 512 + colE;
  const int ldsOff = w * 512;   // elems; + c*2048; HW adds lane*16B

  for (int kt = 0; kt < 512; kt += 64) {
    #pragma unroll
    for (int c = 0; c < 4; ++c) {
      gld16(Abase + (size_t)(c * 32) * 512 + kt, lA + c * 2048 + ldsOff);
      gld16(Bbase + (size_t)(c * 32) * 512 + kt, lB + c * 2048 + ldsOff);
    }
    __syncthreads();
    #pragma unroll
    for (int kk = 0; kk < 2; ++kk) {
      bf16x8_t af[4], bfr[4];
      #pragma unroll
      for (int f = 0; f < 4; ++f) {
        int arow = wm * 64 + f * 16 + (l & 15);
        af[f] = *(const bf16x8_t*)(lA + arow * 64 + kk * 32 + (l >> 4) * 8);
        int brow = wn * 64 + f * 16 + (l & 15);
        bfr[f] = *(const bf16x8_t*)(lB + brow * 64 + kk * 32 + (l >> 4) * 8);
      }
      #pragma unroll
      for (int i = 0; i < 4; ++i)
        #pragma unroll
        for (int j = 0; j < 4; ++j)
          acc[i][j] = __builtin_amdgcn_mfma_f32_16x16x32_bf16(af[i], bfr[j], acc[i][j], 0, 0, 0);
    }
    __syncthreads();
  }

  // epilogue: bias + exact GELU, stage bf16 to LDS, atomic sumsq per column
  const int lrow = (l >> 4) * 4;
  const int lcol = l & 15;
  float bj[4];
  #pragma unroll
  for (int j = 0; j < 4; ++j) bj[j] = b1[n0 + wn * 64 + j * 16 + lcol];

  float ss[4] = {0.f, 0.f, 0.f, 0.f};
  #pragma unroll
  for (int i = 0; i < 4; ++i) {
    int row = wm * 64 + i * 16 + lrow;
    #pragma unroll
    for (int j = 0; j < 4; ++j) {
      int col = wn * 64 + j * 16 + lcol;
      #pragma unroll
      for (int r = 0; r < 4; ++r) {
        float v = acc[i][j][r] + bj[j];
        float g = 0.5f * v * (1.0f + erff(v * 0.70710678118654752f));
        ss[j] += g * g;
        smem[(row + r) * 136 + col] = f2bf(g);
      }
    }
  }
  #pragma unroll
  for (int j = 0; j < 4; ++j) {
    float v = ss[j];
    v += __shfl_xor(v, 16);
    v += __shfl_xor(v, 32);
    if ((l >> 4) == 0)
      atomicAdd(&gsum[bidx * 1536 + n0 + wn * 64 + j * 16 + lcol], v);
  }
  __syncthreads();
  #pragma unroll
  for (int it = 0; it < 8; ++it) {
    int idx = it * 256 + tid;   // 0..2047
    int row = idx >> 4;         // 0..127
    int cb = idx & 15;
    uint4 v = *(const uint4*)(smem + row * 136 + cb * 8);
    *(uint4*)(H + (size_t)(m0 + row) * 1536 + n0 + cb * 8) = v;
  }
}

// ---------------------------------------------------------------------------
// GRN scale: s[b][i] = 1 + grn_g[i] * gx / (mean_i(gx) + 1e-6), gx = sqrt(gsum)
__global__ __launch_bounds__(256) void grn_kernel(const float* __restrict__ gsum,
                                                  const float* __restrict__ grn_g,
                                                  float* __restrict__ svec) {
  __shared__ float red[256];
  int b = blockIdx.x, tid = threadIdx.x;
  float gx[6];
  float part = 0.f;
  #pragma unroll
  for (int it = 0; it < 6; ++it) {
    int i = it * 256 + tid;
    gx[it] = sqrtf(gsum[b * 1536 + i]);
    part += gx[it];
  }
  red[tid] = part;
  __syncthreads();
  for (int s = 128; s; s >>= 1) {
    if (tid < s) red[tid] += red[tid + s];
    __syncthreads();
  }
  float inv = 1.0f / (red[0] * (1.f / 1536.f) + 1e-6f);
  #pragma unroll
  for (int it = 0; it < 6; ++it) {
    int i = it * 256 + tid;
    svec[b * 1536 + i] = 1.0f + grn_g[i] * gx[it] * inv;
  }
}

// ---------------------------------------------------------------------------
// GEMM2: out[b][c][t] = x[b][c][t] + (h[m][:] * s[b][:]) . w2[c][:] + b2ob[c]
// M=32768 K=1536 N=512.  A reg-staged (scale applied), B via global_load_lds.
__global__ __launch_bounds__(256, 2) void gemm2_kernel(const u16* __restrict__ Hs,
                                                       const u16* __restrict__ B,
                                                       const float* __restrict__ svec,
                                                       const float* __restrict__ b2ob,
                                                       const float* __restrict__ X,
                                                       float* __restrict__ Out) {
  __shared__ __align__(16) u16 smem[16512];  // tiles 2x8192 u16 (32KB); ostage 64x129 f32 (33024B)
  u16* lA = smem;
  u16* lB = smem + 8192;

  const int tid = threadIdx.x;
  const int w = tid >> 6;
  const int l = tid & 63;
  const int m0 = blockIdx.x * 128;
  const int n0 = blockIdx.y * 128;
  const int bidx = m0 >> 11;
  const int t0 = m0 & 2047;
  const int wm = w >> 1, wn = w & 1;

  f32x4_t acc[4][4];
  #pragma unroll
  for (int i = 0; i < 4; ++i)
    #pragma unroll
    for (int j = 0; j < 4; ++j) {
      f32x4_t z = {0.f, 0.f, 0.f, 0.f};
      acc[i][j] = z;
    }

  const int rowInc = w * 8 + (l >> 3);
  const int colE = (l & 7) * 8;
  const u16* Abase = Hs + (size_t)(m0 + rowInc) * 1536 + colE;
  const u16* Bbase = B + (size_t)(n0 + rowInc) * 1536 + colE;
  const float* sb = svec + bidx * 1536 + colE;
  const int ldsOff = w * 512;

  for (int kt = 0; kt < 1536; kt += 64) {
    // B tile: async direct-to-LDS
    #pragma unroll
    for (int c = 0; c < 4; ++c)
      gld16(Bbase + (size_t)(c * 32) * 1536 + kt, lB + c * 2048 + ldsOff);
    // A tile: reg-staged with GRN scale folded in
    float4 s0 = *(const float4*)(sb + kt);
    float4 s1 = *(const float4*)(sb + kt + 4);
    float sv[8] = {s0.x, s0.y, s0.z, s0.w, s1.x, s1.y, s1.z, s1.w};
    #pragma unroll
    for (int c = 0; c < 4; ++c) {
      bf16x8_t hv = *(const bf16x8_t*)(Abase + (size_t)(c * 32) * 1536 + kt);
      bf16x8_t ov;
      #pragma unroll
      for (int e = 0; e < 8; ++e) ov[e] = (__bf16)((float)hv[e] * sv[e]);
      *(bf16x8_t*)(lA + c * 2048 + ldsOff + l * 8) = ov;
    }
    __syncthreads();
    #pragma unroll
    for (int kk = 0; kk < 2; ++kk) {
      bf16x8_t af[4], bfr[4];
      #pragma unroll
      for (int f = 0; f < 4; ++f) {
        int arow = wm * 64 + f * 16 + (l & 15);
        af[f] = *(const bf16x8_t*)(lA + arow * 64 + kk * 32 + (l >> 4) * 8);
        int brow = wn * 64 + f * 16 + (l & 15);
        bfr[f] = *(const bf16x8_t*)(lB + brow * 64 + kk * 32 + (l >> 4) * 8);
      }
      #pragma unroll
      for (int i = 0; i < 4; ++i)
        #pragma unroll
        for (int j = 0; j < 4; ++j)
          acc[i][j] = __builtin_amdgcn_mfma_f32_16x16x32_bf16(af[i], bfr[j], acc[i][j], 0, 0, 0);
    }
    __syncthreads();
  }

  // epilogue: transpose through LDS (fp32, stride 129 -> conflict-free col read),
  // add b2ob + residual, write out[b][c][t]
  float* ostage = (float*)smem;
  #pragma unroll
  for (int half = 0; half < 2; ++half) {
    if (wm == half) {
      #pragma unroll
      for (int i = 0; i < 4; ++i) {
        int lr = i * 16 + (l >> 4) * 4;   // 0..63 within half
        #pragma unroll
        for (int j = 0; j < 4; ++j) {
          int col = wn * 64 + j * 16 + (l & 15);
          #pragma unroll
          for (int r = 0; r < 4; ++r) ostage[(lr + r) * 129 + col] = acc[i][j][r];
        }
      }
    }
    __syncthreads();
    #pragma unroll
    for (int it = 0; it < 32; ++it) {
      int cl = it * 4 + w;      // 0..127
      int c = n0 + cl;
      float v = ostage[l * 129 + cl];
      size_t oidx = ((size_t)bidx * 512 + c) * 2048 + t0 + half * 64 + l;
      Out[oidx] = v + b2ob[c] + X[oidx];
    }
    __syncthreads();
  }
}

// ---------------------------------------------------------------------------
extern "C" void kernel_launch(void* const* d_in, const int* in_sizes, int n_in,
                              void* d_out, int out_size, void* d_ws, size_t ws_size,
                              hipStream_t stream) {
  const float* x     = (const float*)d_in[0];
  const float* dw_w  = (const float*)d_in[1];
  const float* dw_b  = (const float*)d_in[2];
  const float* ln_g  = (const float*)d_in[3];
  const float* ln_b  = (const float*)d_in[4];
  const float* w1    = (const float*)d_in[5];
  const float* b1    = (const float*)d_in[6];
  const float* grn_g = (const float*)d_in[7];
  const float* grn_b = (const float*)d_in[8];
  const float* w2    = (const float*)d_in[9];
  const float* b2    = (const float*)d_in[10];
  float* out = (float*)d_out;

  // workspace layout (all 16B aligned)
  u16* y_ln = (u16*)d_ws;                             // 32768*512
  u16* h    = y_ln + (size_t)32768 * 512;             // 32768*1536
  u16* w1b  = h + (size_t)32768 * 1536;               // 1536*512
  u16* w2b  = w1b + (size_t)1536 * 512;               // 512*1536
  float* gsum = (float*)(w2b + (size_t)512 * 1536);   // 16*1536
  float* svec = gsum + 16 * 1536;                     // 16*1536
  float* b2ob = svec + 16 * 1536;                     // 512

  hipMemsetAsync(gsum, 0, 16 * 1536 * sizeof(float), stream);
  cast_kernel<<<768, 256, 0, stream>>>(w1, w1b, 1536 * 512);
  cast_kernel<<<768, 256, 0, stream>>>(w2, w2b, 512 * 1536);
  b2ob_kernel<<<512, 64, 0, stream>>>(w2, grn_b, b2, b2ob);
  conv_ln_kernel<<<dim3(128, 16), 256, 0, stream>>>(x, dw_w, dw_b, ln_g, ln_b, y_ln);
  gemm1_kernel<<<dim3(256, 12), 256, 0, stream>>>(y_ln, w1b, b1, h, gsum);
  grn_kernel<<<16, 256, 0, stream>>>(gsum, grn_g, svec);
  gemm2_kernel<<<dim3(256, 4), 256, 0, stream>>>(h, w2b, svec, b2ob, x, out);
}

// Round 4
// 269.579 us; speedup vs baseline: 1.2513x; 1.2454x over previous
//
#include <hip/hip_runtime.h>
#include <math.h>

typedef unsigned short u16;
typedef unsigned int u32;
typedef __bf16 bf16x8_t __attribute__((ext_vector_type(8)));
typedef float f32x4_t __attribute__((ext_vector_type(4)));

__device__ __forceinline__ u16 f2bf(float f) {
  __bf16 b = (__bf16)f;
  return __builtin_bit_cast(u16, b);
}

__device__ __forceinline__ void gld16(const void* g, void* l) {
  __builtin_amdgcn_global_load_lds(
      (const __attribute__((address_space(1))) void*)g,
      (__attribute__((address_space(3))) void*)l, 16, 0, 0);
}

// ---------------------------------------------------------------------------
// cast fp32 -> bf16 (weights)
__global__ __launch_bounds__(256) void cast_kernel(const float* __restrict__ src,
                                                   u16* __restrict__ dst, int n) {
  int i = (blockIdx.x * 256 + threadIdx.x) * 4;
  if (i < n) {
    float4 v = *(const float4*)(src + i);
    uint2 o;
    o.x = (u32)f2bf(v.x) | ((u32)f2bf(v.y) << 16);
    o.y = (u32)f2bf(v.z) | ((u32)f2bf(v.w) << 16);
    *(uint2*)(dst + i) = o;
  }
}

// ---------------------------------------------------------------------------
// b2ob[c] = b2[c] + sum_i grn_b[i]*w2[c][i]
__global__ __launch_bounds__(64) void b2ob_kernel(const float* __restrict__ w2,
                                                  const float* __restrict__ grn_b,
                                                  const float* __restrict__ b2,
                                                  float* __restrict__ out) {
  int c = blockIdx.x;
  int l = threadIdx.x;
  float p = 0.f;
  for (int i = l; i < 1536; i += 64) p += grn_b[i] * w2[(size_t)c * 1536 + i];
  #pragma unroll
  for (int s = 32; s; s >>= 1) p += __shfl_xor(p, s);
  if (l == 0) out[c] = b2[c] + p;
}

// ---------------------------------------------------------------------------
// depthwise conv (K=7, pad 3) + LayerNorm over C, output bf16 [B*T][512]
// One thread per channel; t-tile 64 per block in 4 chunks of 16.
// Per chunk: thread loads 24-float window (6 aligned float4), computes 16
// conv outputs in regs, stages fp32 to LDS for the cross-channel LN
// reduction, then normalizes from regs and stores bf16 (coalesced, 2B/lane).
__global__ __launch_bounds__(512, 4) void conv_ln_kernel(const float* __restrict__ X,
                                                         const float* __restrict__ Wd,
                                                         const float* __restrict__ bd,
                                                         const float* __restrict__ lng,
                                                         const float* __restrict__ lnb,
                                                         u16* __restrict__ Y) {
  __shared__ float ystage[16 * 516];   // [t-row][channel], +4 pad
  __shared__ float mu_s[16], rs_s[16];

  const int c = threadIdx.x;           // channel 0..511
  const int b = blockIdx.y;
  const int t0 = blockIdx.x * 64;

  const float* xr = X + ((size_t)b * 512 + c) * 2048;
  float wr[7];
  #pragma unroll
  for (int k = 0; k < 7; ++k) wr[k] = Wd[c * 7 + k];
  const float bdv = bd[c];
  const float lg = lng[c];
  const float lb = lnb[c];

  for (int ch = 0; ch < 4; ++ch) {
    const int tc0 = t0 + ch * 16;
    const int g = tc0 - 4;             // window start; g%4==0 -> 16B aligned
    float w[24];
    if (g >= 0 && g + 24 <= 2048) {
      #pragma unroll
      for (int q = 0; q < 6; ++q) {
        float4 v = *(const float4*)(xr + g + q * 4);
        w[q * 4 + 0] = v.x; w[q * 4 + 1] = v.y;
        w[q * 4 + 2] = v.z; w[q * 4 + 3] = v.w;
      }
    } else {                           // block-uniform slow path (grid edges)
      #pragma unroll
      for (int j = 0; j < 24; ++j) {
        int tt = g + j;
        w[j] = (tt >= 0 && tt < 2048) ? xr[tt] : 0.f;
      }
    }
    float outv[16];
    #pragma unroll
    for (int i = 0; i < 16; ++i) {
      float a = bdv;
      #pragma unroll
      for (int k = 0; k < 7; ++k) a = fmaf(w[i + 1 + k], wr[k], a);
      outv[i] = a;
      ystage[i * 516 + c] = a;
    }
    __syncthreads();
    {
      // 32 threads per t-row reduce 512 channels
      int r = c >> 5, cl = c & 31;
      float s = 0.f, q = 0.f;
      #pragma unroll
      for (int k = 0; k < 16; ++k) {
        float v = ystage[r * 516 + cl + k * 32];
        s += v; q += v * v;
      }
      #pragma unroll
      for (int m = 16; m; m >>= 1) { s += __shfl_xor(s, m); q += __shfl_xor(q, m); }
      if (cl == 0) {
        float mu = s * (1.f / 512.f);
        float var = q * (1.f / 512.f) - mu * mu;
        mu_s[r] = mu;
        rs_s[r] = rsqrtf(var + 1e-6f);
      }
    }
    __syncthreads();
    #pragma unroll
    for (int i = 0; i < 16; ++i) {
      float v = (outv[i] - mu_s[i]) * rs_s[i] * lg + lb;
      Y[(size_t)(b * 2048 + tc0 + i) * 512 + c] = f2bf(v);
    }
    // next chunk's ystage writes are safe: every thread reads mu_s/rs_s
    // (not ystage) after the 2nd barrier, and mu_s is only rewritten after
    // the next chunk's 1st barrier.
  }
}

// ---------------------------------------------------------------------------
// GEMM1: h[m][n] = gelu( y_ln[m][:] . w1[n][:] + b1[n] ), M=32768 K=512 N=1536
// also accumulates gsum[b][n] += sum_rows gelu^2 (for GRN)
__global__ __launch_bounds__(256, 2) void gemm1_kernel(const u16* __restrict__ A,
                                                       const u16* __restrict__ B,
                                                       const float* __restrict__ b1,
                                                       u16* __restrict__ H,
                                                       float* __restrict__ gsum) {
  __shared__ __align__(16) u16 smem[128 * 136];   // tiles: 2x 128*64; epilogue stage 128x136
  u16* lA = smem;
  u16* lB = smem + 128 * 64;

  const int tid = threadIdx.x;
  const int w = tid >> 6;
  const int l = tid & 63;
  const int m0 = blockIdx.x * 128;
  const int n0 = blockIdx.y * 128;
  const int bidx = m0 >> 11;
  const int wm = w >> 1, wn = w & 1;

  f32x4_t acc[4][4];
  #pragma unroll
  for (int i = 0; i < 4; ++i)
    #pragma unroll
    for (int j = 0; j < 4; ++j) {
      f32x4_t z = {0.f, 0.f, 0.f, 0.f};
      acc[i][j] = z;
    }

  const int rowInc = w * 8 + (l >> 3);
  const int colE = (l & 7) * 8;
  const u16* Abase = A + (size_t)(m0 + rowInc) * 512 + colE;
  const u16* Bbase = B + (size_t)(n0 + rowInc) * 512 + colE;
  const int ldsOff = w * 512;   // elems; + c*2048; HW adds lane*16B

  for (int kt = 0; kt < 512; kt += 64) {
    #pragma unroll
    for (int c = 0; c < 4; ++c) {
      gld16(Abase + (size_t)(c * 32) * 512 + kt, lA + c * 2048 + ldsOff);
      gld16(Bbase + (size_t)(c * 32) * 512 + kt, lB + c * 2048 + ldsOff);
    }
    __syncthreads();
    #pragma unroll
    for (int kk = 0; kk < 2; ++kk) {
      bf16x8_t af[4], bfr[4];
      #pragma unroll
      for (int f = 0; f < 4; ++f) {
        int arow = wm * 64 + f * 16 + (l & 15);
        af[f] = *(const bf16x8_t*)(lA + arow * 64 + kk * 32 + (l >> 4) * 8);
        int brow = wn * 64 + f * 16 + (l & 15);
        bfr[f] = *(const bf16x8_t*)(lB + brow * 64 + kk * 32 + (l >> 4) * 8);
      }
      #pragma unroll
      for (int i = 0; i < 4; ++i)
        #pragma unroll
        for (int j = 0; j < 4; ++j)
          acc[i][j] = __builtin_amdgcn_mfma_f32_16x16x32_bf16(af[i], bfr[j], acc[i][j], 0, 0, 0);
    }
    __syncthreads();
  }

  // epilogue: bias + exact GELU, stage bf16 to LDS, atomic sumsq per column
  const int lrow = (l >> 4) * 4;
  const int lcol = l & 15;
  float bj[4];
  #pragma unroll
  for (int j = 0; j < 4; ++j) bj[j] = b1[n0 + wn * 64 + j * 16 + lcol];

  float ss[4] = {0.f, 0.f, 0.f, 0.f};
  #pragma unroll
  for (int i = 0; i < 4; ++i) {
    int row = wm * 64 + i * 16 + lrow;
    #pragma unroll
    for (int j = 0; j < 4; ++j) {
      int col = wn * 64 + j * 16 + lcol;
      #pragma unroll
      for (int r = 0; r < 4; ++r) {
        float v = acc[i][j][r] + bj[j];
        float g = 0.5f * v * (1.0f + erff(v * 0.70710678118654752f));
        ss[j] += g * g;
        smem[(row + r) * 136 + col] = f2bf(g);
      }
    }
  }
  #pragma unroll
  for (int j = 0; j < 4; ++j) {
    float v = ss[j];
    v += __shfl_xor(v, 16);
    v += __shfl_xor(v, 32);
    if ((l >> 4) == 0)
      atomicAdd(&gsum[bidx * 1536 + n0 + wn * 64 + j * 16 + lcol], v);
  }
  __syncthreads();
  #pragma unroll
  for (int it = 0; it < 8; ++it) {
    int idx = it * 256 + tid;   // 0..2047
    int row = idx >> 4;         // 0..127
    int cb = idx & 15;
    uint4 v = *(const uint4*)(smem + row * 136 + cb * 8);
    *(uint4*)(H + (size_t)(m0 + row) * 1536 + n0 + cb * 8) = v;
  }
}

// ---------------------------------------------------------------------------
// GRN scale: s[b][i] = 1 + grn_g[i] * gx / (mean_i(gx) + 1e-6), gx = sqrt(gsum)
__global__ __launch_bounds__(256) void grn_kernel(const float* __restrict__ gsum,
                                                  const float* __restrict__ grn_g,
                                                  float* __restrict__ svec) {
  __shared__ float red[256];
  int b = blockIdx.x, tid = threadIdx.x;
  float gx[6];
  float part = 0.f;
  #pragma unroll
  for (int it = 0; it < 6; ++it) {
    int i = it * 256 + tid;
    gx[it] = sqrtf(gsum[b * 1536 + i]);
    part += gx[it];
  }
  red[tid] = part;
  __syncthreads();
  for (int s = 128; s; s >>= 1) {
    if (tid < s) red[tid] += red[tid + s];
    __syncthreads();
  }
  float inv = 1.0f / (red[0] * (1.f / 1536.f) + 1e-6f);
  #pragma unroll
  for (int it = 0; it < 6; ++it) {
    int i = it * 256 + tid;
    svec[b * 1536 + i] = 1.0f + grn_g[i] * gx[it] * inv;
  }
}

// ---------------------------------------------------------------------------
// GEMM2: out[b][c][t] = x[b][c][t] + (h[m][:] * s[b][:]) . w2[c][:] + b2ob[c]
// M=32768 K=1536 N=512.  A reg-staged (scale applied), B via global_load_lds.
__global__ __launch_bounds__(256, 2) void gemm2_kernel(const u16* __restrict__ Hs,
                                                       const u16* __restrict__ B,
                                                       const float* __restrict__ svec,
                                                       const float* __restrict__ b2ob,
                                                       const float* __restrict__ X,
                                                       float* __restrict__ Out) {
  __shared__ __align__(16) u16 smem[16512];  // tiles 2x8192 u16 (32KB); ostage 64x129 f32 (33024B)
  u16* lA = smem;
  u16* lB = smem + 8192;

  const int tid = threadIdx.x;
  const int w = tid >> 6;
  const int l = tid & 63;
  const int m0 = blockIdx.x * 128;
  const int n0 = blockIdx.y * 128;
  const int bidx = m0 >> 11;
  const int t0 = m0 & 2047;
  const int wm = w >> 1, wn = w & 1;

  f32x4_t acc[4][4];
  #pragma unroll
  for (int i = 0; i < 4; ++i)
    #pragma unroll
    for (int j = 0; j < 4; ++j) {
      f32x4_t z = {0.f, 0.f, 0.f, 0.f};
      acc[i][j] = z;
    }

  const int rowInc = w * 8 + (l >> 3);
  const int colE = (l & 7) * 8;
  const u16* Abase = Hs + (size_t)(m0 + rowInc) * 1536 + colE;
  const u16* Bbase = B + (size_t)(n0 + rowInc) * 1536 + colE;
  const float* sb = svec + bidx * 1536 + colE;
  const int ldsOff = w * 512;

  for (int kt = 0; kt < 1536; kt += 64) {
    // B tile: async direct-to-LDS
    #pragma unroll
    for (int c = 0; c < 4; ++c)
      gld16(Bbase + (size_t)(c * 32) * 1536 + kt, lB + c * 2048 + ldsOff);
    // A tile: reg-staged with GRN scale folded in
    float4 s0 = *(const float4*)(sb + kt);
    float4 s1 = *(const float4*)(sb + kt + 4);
    float sv[8] = {s0.x, s0.y, s0.z, s0.w, s1.x, s1.y, s1.z, s1.w};
    #pragma unroll
    for (int c = 0; c < 4; ++c) {
      bf16x8_t hv = *(const bf16x8_t*)(Abase + (size_t)(c * 32) * 1536 + kt);
      bf16x8_t ov;
      #pragma unroll
      for (int e = 0; e < 8; ++e) ov[e] = (__bf16)((float)hv[e] * sv[e]);
      *(bf16x8_t*)(lA + c * 2048 + ldsOff + l * 8) = ov;
    }
    __syncthreads();
    #pragma unroll
    for (int kk = 0; kk < 2; ++kk) {
      bf16x8_t af[4], bfr[4];
      #pragma unroll
      for (int f = 0; f < 4; ++f) {
        int arow = wm * 64 + f * 16 + (l & 15);
        af[f] = *(const bf16x8_t*)(lA + arow * 64 + kk * 32 + (l >> 4) * 8);
        int brow = wn * 64 + f * 16 + (l & 15);
        bfr[f] = *(const bf16x8_t*)(lB + brow * 64 + kk * 32 + (l >> 4) * 8);
      }
      #pragma unroll
      for (int i = 0; i < 4; ++i)
        #pragma unroll
        for (int j = 0; j < 4; ++j)
          acc[i][j] = __builtin_amdgcn_mfma_f32_16x16x32_bf16(af[i], bfr[j], acc[i][j], 0, 0, 0);
    }
    __syncthreads();
  }

  // epilogue: transpose through LDS (fp32, stride 129 -> conflict-free col read),
  // add b2ob + residual, write out[b][c][t]
  float* ostage = (float*)smem;
  #pragma unroll
  for (int half = 0; half < 2; ++half) {
    if (wm == half) {
      #pragma unroll
      for (int i = 0; i < 4; ++i) {
        int lr = i * 16 + (l >> 4) * 4;   // 0..63 within half
        #pragma unroll
        for (int j = 0; j < 4; ++j) {
          int col = wn * 64 + j * 16 + (l & 15);
          #pragma unroll
          for (int r = 0; r < 4; ++r) ostage[(lr + r) * 129 + col] = acc[i][j][r];
        }
      }
    }
    __syncthreads();
    #pragma unroll
    for (int it = 0; it < 32; ++it) {
      int cl = it * 4 + w;      // 0..127
      int c = n0 + cl;
      float v = ostage[l * 129 + cl];
      size_t oidx = ((size_t)bidx * 512 + c) * 2048 + t0 + half * 64 + l;
      Out[oidx] = v + b2ob[c] + X[oidx];
    }
    __syncthreads();
  }
}

// ---------------------------------------------------------------------------
extern "C" void kernel_launch(void* const* d_in, const int* in_sizes, int n_in,
                              void* d_out, int out_size, void* d_ws, size_t ws_size,
                              hipStream_t stream) {
  const float* x     = (const float*)d_in[0];
  const float* dw_w  = (const float*)d_in[1];
  const float* dw_b  = (const float*)d_in[2];
  const float* ln_g  = (const float*)d_in[3];
  const float* ln_b  = (const float*)d_in[4];
  const float* w1    = (const float*)d_in[5];
  const float* b1    = (const float*)d_in[6];
  const float* grn_g = (const float*)d_in[7];
  const float* grn_b = (const float*)d_in[8];
  const float* w2    = (const float*)d_in[9];
  const float* b2    = (const float*)d_in[10];
  float* out = (float*)d_out;

  // workspace layout (all 16B aligned)
  u16* y_ln = (u16*)d_ws;                             // 32768*512
  u16* h    = y_ln + (size_t)32768 * 512;             // 32768*1536
  u16* w1b  = h + (size_t)32768 * 1536;               // 1536*512
  u16* w2b  = w1b + (size_t)1536 * 512;               // 512*1536
  float* gsum = (float*)(w2b + (size_t)512 * 1536);   // 16*1536
  float* svec = gsum + 16 * 1536;                     // 16*1536
  float* b2ob = svec + 16 * 1536;                     // 512

  hipMemsetAsync(gsum, 0, 16 * 1536 * sizeof(float), stream);
  cast_kernel<<<768, 256, 0, stream>>>(w1, w1b, 1536 * 512);
  cast_kernel<<<768, 256, 0, stream>>>(w2, w2b, 512 * 1536);
  b2ob_kernel<<<512, 64, 0, stream>>>(w2, grn_b, b2, b2ob);
  conv_ln_kernel<<<dim3(32, 16), 512, 0, stream>>>(x, dw_w, dw_b, ln_g, ln_b, y_ln);
  gemm1_kernel<<<dim3(256, 12), 256, 0, stream>>>(y_ln, w1b, b1, h, gsum);
  grn_kernel<<<16, 256, 0, stream>>>(gsum, grn_g, svec);
  gemm2_kernel<<<dim3(256, 4), 256, 0, stream>>>(h, w2b, svec, b2ob, x, out);
}

// Round 5
// 248.211 us; speedup vs baseline: 1.3590x; 1.0861x over previous
//
#include <hip/hip_runtime.h>
#include <math.h>

typedef unsigned short u16;
typedef unsigned int u32;
typedef __bf16 bf16x8_t __attribute__((ext_vector_type(8)));
typedef float f32x4_t __attribute__((ext_vector_type(4)));

#define MEMF() asm volatile("" ::: "memory")
__device__ __forceinline__ void bar() {
  MEMF();
  __builtin_amdgcn_s_barrier();
  MEMF();
}

__device__ __forceinline__ u16 f2bf(float f) {
  __bf16 b = (__bf16)f;
  return __builtin_bit_cast(u16, b);
}

__device__ __forceinline__ void gld16(const void* g, void* l) {
  __builtin_amdgcn_global_load_lds(
      (const __attribute__((address_space(1))) void*)g,
      (__attribute__((address_space(3))) void*)l, 16, 0, 0);
}

// tanh-form GELU (max abs dev from exact erf-GELU ~1e-3, << bf16 rounding)
__device__ __forceinline__ float gelu_f(float v) {
  float z = 0.7978845608028654f * (v + 0.044715f * v * v * v);
  float zc = fminf(fmaxf(z, -15.f), 15.f);
  float t = __builtin_amdgcn_exp2f(2.8853900817779268f * zc);  // e^(2z)
  float th = (t - 1.f) / (t + 1.f);
  return 0.5f * v * (1.f + th);
}

__device__ __forceinline__ int swz8(int bid, int nwg) {
  int cpx = nwg >> 3;                 // requires nwg % 8 == 0
  return (bid & 7) * cpx + (bid >> 3);
}

// ---------------------------------------------------------------------------
// cast fp32 -> bf16 (w1)
__global__ __launch_bounds__(256) void cast_kernel(const float* __restrict__ src,
                                                   u16* __restrict__ dst, int n) {
  int i = (blockIdx.x * 256 + threadIdx.x) * 4;
  if (i < n) {
    float4 v = *(const float4*)(src + i);
    uint2 o;
    o.x = (u32)f2bf(v.x) | ((u32)f2bf(v.y) << 16);
    o.y = (u32)f2bf(v.z) | ((u32)f2bf(v.w) << 16);
    *(uint2*)(dst + i) = o;
  }
}

// ---------------------------------------------------------------------------
// b2ob[c] = b2[c] + sum_i grn_b[i]*w2[c][i]
__global__ __launch_bounds__(64) void b2ob_kernel(const float* __restrict__ w2,
                                                  const float* __restrict__ grn_b,
                                                  const float* __restrict__ b2,
                                                  float* __restrict__ out) {
  int c = blockIdx.x;
  int l = threadIdx.x;
  float p = 0.f;
  for (int i = l; i < 1536; i += 64) p += grn_b[i] * w2[(size_t)c * 1536 + i];
  #pragma unroll
  for (int s = 32; s; s >>= 1) p += __shfl_xor(p, s);
  if (l == 0) out[c] = b2[c] + p;
}

// ---------------------------------------------------------------------------
// depthwise conv (K=7, pad 3) + LayerNorm over C, output bf16 [B*T][512]
__global__ __launch_bounds__(512, 4) void conv_ln_kernel(const float* __restrict__ X,
                                                         const float* __restrict__ Wd,
                                                         const float* __restrict__ bd,
                                                         const float* __restrict__ lng,
                                                         const float* __restrict__ lnb,
                                                         u16* __restrict__ Y) {
  __shared__ float ystage[16 * 516];
  __shared__ float mu_s[16], rs_s[16];

  const int c = threadIdx.x;
  const int b = blockIdx.y;
  const int t0 = blockIdx.x * 64;

  const float* xr = X + ((size_t)b * 512 + c) * 2048;
  float wr[7];
  #pragma unroll
  for (int k = 0; k < 7; ++k) wr[k] = Wd[c * 7 + k];
  const float bdv = bd[c];
  const float lg = lng[c];
  const float lb = lnb[c];

  for (int ch = 0; ch < 4; ++ch) {
    const int tc0 = t0 + ch * 16;
    const int g = tc0 - 4;
    float w[24];
    if (g >= 0 && g + 24 <= 2048) {
      #pragma unroll
      for (int q = 0; q < 6; ++q) {
        float4 v = *(const float4*)(xr + g + q * 4);
        w[q * 4 + 0] = v.x; w[q * 4 + 1] = v.y;
        w[q * 4 + 2] = v.z; w[q * 4 + 3] = v.w;
      }
    } else {
      #pragma unroll
      for (int j = 0; j < 24; ++j) {
        int tt = g + j;
        w[j] = (tt >= 0 && tt < 2048) ? xr[tt] : 0.f;
      }
    }
    float outv[16];
    #pragma unroll
    for (int i = 0; i < 16; ++i) {
      float a = bdv;
      #pragma unroll
      for (int k = 0; k < 7; ++k) a = fmaf(w[i + 1 + k], wr[k], a);
      outv[i] = a;
      ystage[i * 516 + c] = a;
    }
    __syncthreads();
    {
      int r = c >> 5, cl = c & 31;
      float s = 0.f, q = 0.f;
      #pragma unroll
      for (int k = 0; k < 16; ++k) {
        float v = ystage[r * 516 + cl + k * 32];
        s += v; q += v * v;
      }
      #pragma unroll
      for (int m = 16; m; m >>= 1) { s += __shfl_xor(s, m); q += __shfl_xor(q, m); }
      if (cl == 0) {
        float mu = s * (1.f / 512.f);
        float var = q * (1.f / 512.f) - mu * mu;
        mu_s[r] = mu;
        rs_s[r] = rsqrtf(var + 1e-6f);
      }
    }
    __syncthreads();
    #pragma unroll
    for (int i = 0; i < 16; ++i) {
      float v = (outv[i] - mu_s[i]) * rs_s[i] * lg + lb;
      Y[(size_t)(b * 2048 + tc0 + i) * 512 + c] = f2bf(v);
    }
  }
}

// ---------------------------------------------------------------------------
// GRN scale: s[b][i] = 1 + grn_g[i]*gx/(mean(gx)+1e-6)
__global__ __launch_bounds__(256) void grn_kernel(const float* __restrict__ gsum,
                                                  const float* __restrict__ grn_g,
                                                  float* __restrict__ svec) {
  __shared__ float red[256];
  int b = blockIdx.x, tid = threadIdx.x;
  float gx[6];
  float part = 0.f;
  #pragma unroll
  for (int it = 0; it < 6; ++it) {
    int i = it * 256 + tid;
    gx[it] = sqrtf(gsum[b * 1536 + i]);
    part += gx[it];
  }
  red[tid] = part;
  __syncthreads();
  for (int s = 128; s; s >>= 1) {
    if (tid < s) red[tid] += red[tid + s];
    __syncthreads();
  }
  float inv = 1.0f / (red[0] * (1.f / 1536.f) + 1e-6f);
  #pragma unroll
  for (int it = 0; it < 6; ++it) {
    int i = it * 256 + tid;
    svec[b * 1536 + i] = 1.0f + grn_g[i] * gx[it] * inv;
  }
}

// ---------------------------------------------------------------------------
// w2s[b][c][i] = bf16( w2[c][i] * svec[b][i] )   (folds GRN scale into B of GEMM2)
__global__ __launch_bounds__(256) void w2s_kernel(const float* __restrict__ w2,
                                                  const float* __restrict__ svec,
                                                  u16* __restrict__ out) {
  size_t e0 = ((size_t)blockIdx.x * 256 + threadIdx.x) * 8;  // flat into [16][512][1536]
  int i = (int)(e0 % 1536);
  size_t bc = e0 / 1536;
  int b = (int)(bc >> 9);
  size_t widx = (bc & 511) * 1536 + i;
  float4 wa = *(const float4*)(w2 + widx);
  float4 wb = *(const float4*)(w2 + widx + 4);
  float4 sa = *(const float4*)(svec + b * 1536 + i);
  float4 sb = *(const float4*)(svec + b * 1536 + i + 4);
  uint4 o;
  o.x = (u32)f2bf(wa.x * sa.x) | ((u32)f2bf(wa.y * sa.y) << 16);
  o.y = (u32)f2bf(wa.z * sa.z) | ((u32)f2bf(wa.w * sa.w) << 16);
  o.z = (u32)f2bf(wb.x * sb.x) | ((u32)f2bf(wb.y * sb.y) << 16);
  o.w = (u32)f2bf(wb.z * sb.z) | ((u32)f2bf(wb.w * sb.w) << 16);
  *(uint4*)(out + e0) = o;
}

// ---------------------------------------------------------------------------
// 256x256-tile 8-phase bf16 GEMM K-loop (BK=64, 8 waves as 2Mx4N, counted vmcnt,
// XOR-swizzled LDS via pre-swizzled global source). Per-wave C: 128x64.
//
// LDS per buffer (u16): A[256][64] at +0, B[256][64] at +16384; 2 buffers = 128KB.
// Swizzle: logical (row, chunk s of 8 elems) stored at chunk s^(row&7); staging
// fetches global column (chunk^(row&7)) so linear gld16 dest lands swizzled.
//
// Staging ledger (pieces = 2 gld16 each; piece regions disjoint per phase-use):
//   p0: A-mh1(S+1)  p1: B-nh1(S+1)  p2: A-mh0(S+2)  p3: B-nh0(S+2)
// Reads: p0: A-mh0+B-nh0 (12 ds_read), p1: B-nh1 (4), p2: A-mh1 (8), p3: none.
// Every staged region's last LDS-read is >=2 barriers before the stage issue.
// Boundary wait (end of p3): vmcnt(4) covers all of tile S+1 (Bn1(S+1) has
// exactly 4 newer loads: Am0(S+2)+Bn0(S+2)); last tiles drop to vmcnt(0).
template<int KD>
__device__ __forceinline__ void gemm_kloop(const u16* __restrict__ Ag,
                                           const u16* __restrict__ Bg,
                                           u16* lds, int NT,
                                           f32x4_t (&acc)[8][4]) {
  const int tid = threadIdx.x;
  const int l = tid & 63, l15 = l & 15, lq = l >> 4;
  const int w = tid >> 6, wm = w >> 2, wn = w & 3;
  const int rin = tid >> 3;                       // 0..63
  const int cs = ((tid & 7) ^ (rin & 7)) << 3;    // pre-swizzled k-chunk (u16)
  const int strip = (w >> 2) << 6;                // B: waves 4-7 -> +64
  const int rb = rin & 31;
  const int wb8 = (w & 3) << 3;

  auto STAGE_A = [&](int buf, int kt, int mh) {
    u16* lt = lds + buf * 32768;
    gld16(Ag + (size_t)(mh * 64 + rin) * KD + kt + cs,
          lt + (mh * 64 + w * 8) * 64);
    gld16(Ag + (size_t)(128 + mh * 64 + rin) * KD + kt + cs,
          lt + (128 + mh * 64 + w * 8) * 64);
  };
  auto STAGE_B = [&](int buf, int kt, int nh) {
    u16* lt = lds + buf * 32768 + 16384;
    #pragma unroll
    for (int c = 0; c < 2; ++c) {
      int r = c * 128 + strip + nh * 32 + rb;
      gld16(Bg + (size_t)r * KD + kt + cs,
            lt + (c * 128 + strip + nh * 32 + wb8) * 64);
    }
  };

  // prologue: tile0 (4 pieces) + tile1 (Am0,Bn0); vmcnt(4) => tile0 landed
  STAGE_A(0, 0, 0);  STAGE_B(0, 0, 0);
  STAGE_A(0, 0, 1);  STAGE_B(0, 0, 1);
  STAGE_A(1, 64, 0); STAGE_B(1, 64, 0);
  asm volatile("s_waitcnt vmcnt(4)" ::: "memory");
  bar();

  bf16x8_t a[4][2], b0[2][2], b1[2][2];

  for (int S = 0; S < NT; ++S) {
    u16* lA = lds + (S & 1) * 32768;
    u16* lB = lA + 16384;
    const int kt1 = (S + 1) * 64, kt2 = (S + 2) * 64;
    const bool s1 = (S + 1 < NT), s2 = (S + 2 < NT);

    // ---- phase 0: quadrant (mh0, nh0)
    #pragma unroll
    for (int f = 0; f < 4; ++f) {
      const int R = wm * 128 + f * 16 + l15;
      #pragma unroll
      for (int kk = 0; kk < 2; ++kk)
        a[f][kk] = *(const bf16x8_t*)(lA + R * 64 + (((kk * 4 + lq) ^ (R & 7)) << 3));
    }
    #pragma unroll
    for (int g = 0; g < 2; ++g) {
      const int R = wn * 64 + g * 16 + l15;
      #pragma unroll
      for (int kk = 0; kk < 2; ++kk)
        b0[g][kk] = *(const bf16x8_t*)(lB + R * 64 + (((kk * 4 + lq) ^ (R & 7)) << 3));
    }
    if (s1) STAGE_A((S + 1) & 1, kt1, 1);
    bar();
    __builtin_amdgcn_s_setprio(1);
    #pragma unroll
    for (int f = 0; f < 4; ++f)
      #pragma unroll
      for (int g = 0; g < 2; ++g)
        #pragma unroll
        for (int kk = 0; kk < 2; ++kk)
          acc[f][g] = __builtin_amdgcn_mfma_f32_16x16x32_bf16(a[f][kk], b0[g][kk], acc[f][g], 0, 0, 0);
    __builtin_amdgcn_s_setprio(0);
    bar();

    // ---- phase 1: quadrant (mh0, nh1)
    #pragma unroll
    for (int g = 0; g < 2; ++g) {
      const int R = wn * 64 + 32 + g * 16 + l15;
      #pragma unroll
      for (int kk = 0; kk < 2; ++kk)
        b1[g][kk] = *(const bf16x8_t*)(lB + R * 64 + (((kk * 4 + lq) ^ (R & 7)) << 3));
    }
    if (s1) STAGE_B((S + 1) & 1, kt1, 1);
    bar();
    __builtin_amdgcn_s_setprio(1);
    #pragma unroll
    for (int f = 0; f < 4; ++f)
      #pragma unroll
      for (int g = 0; g < 2; ++g)
        #pragma unroll
        for (int kk = 0; kk < 2; ++kk)
          acc[f][2 + g] = __builtin_amdgcn_mfma_f32_16x16x32_bf16(a[f][kk], b1[g][kk], acc[f][2 + g], 0, 0, 0);
    __builtin_amdgcn_s_setprio(0);
    bar();

    // ---- phase 2: quadrant (mh1, nh0)
    #pragma unroll
    for (int f = 0; f < 4; ++f) {
      const int R = wm * 128 + 64 + f * 16 + l15;
      #pragma unroll
      for (int kk = 0; kk < 2; ++kk)
        a[f][kk] = *(const bf16x8_t*)(lA + R * 64 + (((kk * 4 + lq) ^ (R & 7)) << 3));
    }
    if (s2) STAGE_A(S & 1, kt2, 0);
    bar();
    __builtin_amdgcn_s_setprio(1);
    #pragma unroll
    for (int f = 0; f < 4; ++f)
      #pragma unroll
      for (int g = 0; g < 2; ++g)
        #pragma unroll
        for (int kk = 0; kk < 2; ++kk)
          acc[4 + f][g] = __builtin_amdgcn_mfma_f32_16x16x32_bf16(a[f][kk], b0[g][kk], acc[4 + f][g], 0, 0, 0);
    __builtin_amdgcn_s_setprio(0);
    bar();

    // ---- phase 3: quadrant (mh1, nh1)
    if (s2) STAGE_B(S & 1, kt2, 0);
    bar();
    __builtin_amdgcn_s_setprio(1);
    #pragma unroll
    for (int f = 0; f < 4; ++f)
      #pragma unroll
      for (int g = 0; g < 2; ++g)
        #pragma unroll
        for (int kk = 0; kk < 2; ++kk)
          acc[4 + f][2 + g] = __builtin_amdgcn_mfma_f32_16x16x32_bf16(a[f][kk], b1[g][kk], acc[4 + f][2 + g], 0, 0, 0);
    __builtin_amdgcn_s_setprio(0);
    if (s2)      { asm volatile("s_waitcnt vmcnt(4)" ::: "memory"); }
    else if (s1) { asm volatile("s_waitcnt vmcnt(0)" ::: "memory"); }
    bar();
  }
}

// ---------------------------------------------------------------------------
// GEMM1: h = gelu(y_ln . w1^T + b1), M=32768 K=512 N=1536; + gsum column sumsq
__global__ __launch_bounds__(512, 2) void gemm1_kernel(const u16* __restrict__ A,
                                                       const u16* __restrict__ Bw,
                                                       const float* __restrict__ b1,
                                                       u16* __restrict__ H,
                                                       float* __restrict__ gsum) {
  extern __shared__ __align__(16) u16 lds[];
  const int tid = threadIdx.x;
  const int l = tid & 63, l15 = l & 15, lq = l >> 4;
  const int w = tid >> 6, wm = w >> 2, wn = w & 3;
  const int wg = swz8(blockIdx.x, 768);
  const int ntile = wg % 6, mtile = wg / 6;
  const int m0 = mtile * 256, n0 = ntile * 256;
  const int bidx = m0 >> 11;

  f32x4_t acc[8][4];
  #pragma unroll
  for (int i = 0; i < 8; ++i)
    #pragma unroll
    for (int j = 0; j < 4; ++j) {
      f32x4_t z = {0.f, 0.f, 0.f, 0.f};
      acc[i][j] = z;
    }

  gemm_kloop<512>(A + (size_t)m0 * 512, Bw + (size_t)n0 * 512, lds, 8, acc);

  const int coll = wn * 64 + l15;
  float bj[4];
  #pragma unroll
  for (int nf = 0; nf < 4; ++nf) bj[nf] = b1[n0 + coll + nf * 16];

  for (int h = 0; h < 2; ++h) {
    bar();
    if (wm == h) {
      float ss[4] = {0.f, 0.f, 0.f, 0.f};
      #pragma unroll
      for (int mf = 0; mf < 8; ++mf) {
        const int lr = mf * 16 + lq * 4;
        #pragma unroll
        for (int nf = 0; nf < 4; ++nf) {
          #pragma unroll
          for (int r = 0; r < 4; ++r) {
            float g = gelu_f(acc[mf][nf][r] + bj[nf]);
            ss[nf] += g * g;
            lds[(lr + r) * 264 + coll + nf * 16] = f2bf(g);
          }
        }
      }
      #pragma unroll
      for (int nf = 0; nf < 4; ++nf) {
        float v = ss[nf];
        v += __shfl_xor(v, 16);
        v += __shfl_xor(v, 32);
        if (lq == 0) atomicAdd(&gsum[bidx * 1536 + n0 + coll + nf * 16], v);
      }
    }
    bar();
    #pragma unroll
    for (int it = 0; it < 8; ++it) {
      int idx = it * 512 + tid;      // 0..4095 = 128 rows x 32 chunks
      int row = idx >> 5, ch = idx & 31;
      uint4 v = *(const uint4*)(lds + row * 264 + ch * 8);
      *(uint4*)(H + (size_t)(m0 + h * 128 + row) * 1536 + n0 + ch * 8) = v;
    }
  }
}

// ---------------------------------------------------------------------------
// GEMM2: out[b][c][t] = x + h . w2s(b)^T + b2ob[c], M=32768 K=1536 N=512
__global__ __launch_bounds__(512, 2) void gemm2_kernel(const u16* __restrict__ Hm,
                                                       const u16* __restrict__ W2s,
                                                       const float* __restrict__ b2ob,
                                                       const float* __restrict__ X,
                                                       float* __restrict__ Out) {
  extern __shared__ __align__(16) u16 lds[];
  const int tid = threadIdx.x;
  const int l = tid & 63, l15 = l & 15, lq = l >> 4;
  const int w = tid >> 6, wm = w >> 2, wn = w & 3;
  const int wg = swz8(blockIdx.x, 256);
  const int ntile = wg & 1, mtile = wg >> 1;
  const int m0 = mtile * 256, n0 = ntile * 256;
  const int bidx = m0 >> 11, t0 = m0 & 2047;

  f32x4_t acc[8][4];
  #pragma unroll
  for (int i = 0; i < 8; ++i)
    #pragma unroll
    for (int j = 0; j < 4; ++j) {
      f32x4_t z = {0.f, 0.f, 0.f, 0.f};
      acc[i][j] = z;
    }

  gemm_kloop<1536>(Hm + (size_t)m0 * 1536,
                   W2s + ((size_t)bidx * 512 + n0) * 1536, lds, 24, acc);

  // transpose epilogue: 4 quarters of 64 t-rows; fp32 stage [64][261] (conflict-free)
  float* st = (float*)lds;
  for (int q = 0; q < 4; ++q) {
    bar();
    if (wm == (q >> 1)) {
      #pragma unroll
      for (int m2 = 0; m2 < 4; ++m2) {
        const int mf = (q & 1) * 4 + m2;
        const int lr = m2 * 16 + lq * 4;
        #pragma unroll
        for (int nf = 0; nf < 4; ++nf) {
          const int cl = wn * 64 + nf * 16 + l15;
          #pragma unroll
          for (int r = 0; r < 4; ++r)
            st[(lr + r) * 261 + cl] = acc[mf][nf][r];
        }
      }
    }
    bar();
    const size_t obase = ((size_t)bidx * 512 + n0) * 2048 + (size_t)(t0 + q * 64 + l);
    #pragma unroll
    for (int cc = 0; cc < 32; ++cc) {
      const int c = w * 32 + cc;
      float v = st[l * 261 + c] + b2ob[n0 + c];
      size_t oi = obase + (size_t)c * 2048;
      Out[oi] = v + X[oi];
    }
  }
}

// ---------------------------------------------------------------------------
extern "C" void kernel_launch(void* const* d_in, const int* in_sizes, int n_in,
                              void* d_out, int out_size, void* d_ws, size_t ws_size,
                              hipStream_t stream) {
  const float* x     = (const float*)d_in[0];
  const float* dw_w  = (const float*)d_in[1];
  const float* dw_b  = (const float*)d_in[2];
  const float* ln_g  = (const float*)d_in[3];
  const float* ln_b  = (const float*)d_in[4];
  const float* w1    = (const float*)d_in[5];
  const float* b1    = (const float*)d_in[6];
  const float* grn_g = (const float*)d_in[7];
  const float* grn_b = (const float*)d_in[8];
  const float* w2    = (const float*)d_in[9];
  const float* b2    = (const float*)d_in[10];
  float* out = (float*)d_out;

  // workspace layout (w2s overlays y_ln: y_ln is dead after gemm1)
  u16* y_ln = (u16*)d_ws;                             // 32768*512 u16 (33.5MB)
  u16* w2s  = y_ln;                                   // 16*512*1536 u16 (25.2MB)
  u16* h    = y_ln + (size_t)32768 * 512;             // 32768*1536 u16
  u16* w1b  = h + (size_t)32768 * 1536;               // 1536*512 u16
  float* gsum = (float*)(w1b + (size_t)1536 * 512);   // 16*1536 f32
  float* svec = gsum + 16 * 1536;                     // 16*1536 f32
  float* b2ob = svec + 16 * 1536;                     // 512 f32

  (void)hipFuncSetAttribute((const void*)gemm1_kernel,
                            hipFuncAttributeMaxDynamicSharedMemorySize, 131072);
  (void)hipFuncSetAttribute((const void*)gemm2_kernel,
                            hipFuncAttributeMaxDynamicSharedMemorySize, 131072);

  hipMemsetAsync(gsum, 0, 16 * 1536 * sizeof(float), stream);
  cast_kernel<<<768, 256, 0, stream>>>(w1, w1b, 1536 * 512);
  b2ob_kernel<<<512, 64, 0, stream>>>(w2, grn_b, b2, b2ob);
  conv_ln_kernel<<<dim3(32, 16), 512, 0, stream>>>(x, dw_w, dw_b, ln_g, ln_b, y_ln);
  gemm1_kernel<<<768, 512, 131072, stream>>>(y_ln, w1b, b1, h, gsum);
  grn_kernel<<<16, 256, 0, stream>>>(gsum, grn_g, svec);
  w2s_kernel<<<6144, 256, 0, stream>>>(w2, svec, w2s);
  gemm2_kernel<<<256, 512, 131072, stream>>>(h, w2s, b2ob, x, out);
}

// Round 6
// 247.519 us; speedup vs baseline: 1.3628x; 1.0028x over previous
//
#include <hip/hip_runtime.h>
#include <math.h>

typedef unsigned short u16;
typedef unsigned int u32;
typedef __bf16 bf16x8_t __attribute__((ext_vector_type(8)));
typedef float f32x4_t __attribute__((ext_vector_type(4)));

__device__ __forceinline__ u16 f2bf(float f) {
  __bf16 b = (__bf16)f;
  return __builtin_bit_cast(u16, b);
}

__device__ __forceinline__ void gld16(const void* g, void* l) {
  __builtin_amdgcn_global_load_lds(
      (const __attribute__((address_space(1))) void*)g,
      (__attribute__((address_space(3))) void*)l, 16, 0, 0);
}

// tanh-form GELU via rcp: gelu = v * t/(t+1) = v - v*rcp(t+1), t = e^{2z}.
// z->+inf: rcp(inf)=0 -> v.  z->-inf: t=0 -> rcp(1)=1 -> 0.  No clamp needed.
__device__ __forceinline__ float gelu_f(float v) {
  float z = 0.7978845608028654f * v * fmaf(0.044715f, v * v, 1.0f);
  float t = __builtin_amdgcn_exp2f(2.8853900817779268f * z);   // e^{2z}
  float r = __builtin_amdgcn_rcpf(t + 1.0f);
  return v - v * r;
}

__device__ __forceinline__ int swz8(int bid, int nwg) {
  int cpx = nwg >> 3;                 // requires nwg % 8 == 0
  return (bid & 7) * cpx + (bid >> 3);
}

// ---------------------------------------------------------------------------
// cast fp32 -> bf16 (w1)
__global__ __launch_bounds__(256) void cast_kernel(const float* __restrict__ src,
                                                   u16* __restrict__ dst, int n) {
  int i = (blockIdx.x * 256 + threadIdx.x) * 4;
  if (i < n) {
    float4 v = *(const float4*)(src + i);
    uint2 o;
    o.x = (u32)f2bf(v.x) | ((u32)f2bf(v.y) << 16);
    o.y = (u32)f2bf(v.z) | ((u32)f2bf(v.w) << 16);
    *(uint2*)(dst + i) = o;
  }
}

// ---------------------------------------------------------------------------
// b2ob[c] = b2[c] + sum_i grn_b[i]*w2[c][i]
__global__ __launch_bounds__(64) void b2ob_kernel(const float* __restrict__ w2,
                                                  const float* __restrict__ grn_b,
                                                  const float* __restrict__ b2,
                                                  float* __restrict__ out) {
  int c = blockIdx.x;
  int l = threadIdx.x;
  float p = 0.f;
  for (int i = l; i < 1536; i += 64) p += grn_b[i] * w2[(size_t)c * 1536 + i];
  #pragma unroll
  for (int s = 32; s; s >>= 1) p += __shfl_xor(p, s);
  if (l == 0) out[c] = b2[c] + p;
}

// ---------------------------------------------------------------------------
// depthwise conv (K=7, pad 3) + LayerNorm over C, output bf16 [B*T][512]
__global__ __launch_bounds__(512, 4) void conv_ln_kernel(const float* __restrict__ X,
                                                         const float* __restrict__ Wd,
                                                         const float* __restrict__ bd,
                                                         const float* __restrict__ lng,
                                                         const float* __restrict__ lnb,
                                                         u16* __restrict__ Y) {
  __shared__ float ystage[16 * 516];
  __shared__ float mu_s[16], rs_s[16];

  const int c = threadIdx.x;
  const int b = blockIdx.y;
  const int t0 = blockIdx.x * 64;

  const float* xr = X + ((size_t)b * 512 + c) * 2048;
  float wr[7];
  #pragma unroll
  for (int k = 0; k < 7; ++k) wr[k] = Wd[c * 7 + k];
  const float bdv = bd[c];
  const float lg = lng[c];
  const float lb = lnb[c];

  for (int ch = 0; ch < 4; ++ch) {
    const int tc0 = t0 + ch * 16;
    const int g = tc0 - 4;
    float w[24];
    if (g >= 0 && g + 24 <= 2048) {
      #pragma unroll
      for (int q = 0; q < 6; ++q) {
        float4 v = *(const float4*)(xr + g + q * 4);
        w[q * 4 + 0] = v.x; w[q * 4 + 1] = v.y;
        w[q * 4 + 2] = v.z; w[q * 4 + 3] = v.w;
      }
    } else {
      #pragma unroll
      for (int j = 0; j < 24; ++j) {
        int tt = g + j;
        w[j] = (tt >= 0 && tt < 2048) ? xr[tt] : 0.f;
      }
    }
    float outv[16];
    #pragma unroll
    for (int i = 0; i < 16; ++i) {
      float a = bdv;
      #pragma unroll
      for (int k = 0; k < 7; ++k) a = fmaf(w[i + 1 + k], wr[k], a);
      outv[i] = a;
      ystage[i * 516 + c] = a;
    }
    __syncthreads();
    {
      int r = c >> 5, cl = c & 31;
      float s = 0.f, q = 0.f;
      #pragma unroll
      for (int k = 0; k < 16; ++k) {
        float v = ystage[r * 516 + cl + k * 32];
        s += v; q += v * v;
      }
      #pragma unroll
      for (int m = 16; m; m >>= 1) { s += __shfl_xor(s, m); q += __shfl_xor(q, m); }
      if (cl == 0) {
        float mu = s * (1.f / 512.f);
        float var = q * (1.f / 512.f) - mu * mu;
        mu_s[r] = mu;
        rs_s[r] = rsqrtf(var + 1e-6f);
      }
    }
    __syncthreads();
    #pragma unroll
    for (int i = 0; i < 16; ++i) {
      float v = (outv[i] - mu_s[i]) * rs_s[i] * lg + lb;
      Y[(size_t)(b * 2048 + tc0 + i) * 512 + c] = f2bf(v);
    }
  }
}

// ---------------------------------------------------------------------------
// GRN scale: s[b][i] = 1 + grn_g[i]*gx/(mean(gx)+1e-6)
__global__ __launch_bounds__(256) void grn_kernel(const float* __restrict__ gsum,
                                                  const float* __restrict__ grn_g,
                                                  float* __restrict__ svec) {
  __shared__ float red[256];
  int b = blockIdx.x, tid = threadIdx.x;
  float gx[6];
  float part = 0.f;
  #pragma unroll
  for (int it = 0; it < 6; ++it) {
    int i = it * 256 + tid;
    gx[it] = sqrtf(gsum[b * 1536 + i]);
    part += gx[it];
  }
  red[tid] = part;
  __syncthreads();
  for (int s = 128; s; s >>= 1) {
    if (tid < s) red[tid] += red[tid + s];
    __syncthreads();
  }
  float inv = 1.0f / (red[0] * (1.f / 1536.f) + 1e-6f);
  #pragma unroll
  for (int it = 0; it < 6; ++it) {
    int i = it * 256 + tid;
    svec[b * 1536 + i] = 1.0f + grn_g[i] * gx[it] * inv;
  }
}

// ---------------------------------------------------------------------------
// w2s[b][c][i] = bf16( w2[c][i] * svec[b][i] )
__global__ __launch_bounds__(256) void w2s_kernel(const float* __restrict__ w2,
                                                  const float* __restrict__ svec,
                                                  u16* __restrict__ out) {
  size_t e0 = ((size_t)blockIdx.x * 256 + threadIdx.x) * 8;  // flat into [16][512][1536]
  int i = (int)(e0 % 1536);
  size_t bc = e0 / 1536;
  int b = (int)(bc >> 9);
  size_t widx = (bc & 511) * 1536 + i;
  float4 wa = *(const float4*)(w2 + widx);
  float4 wb = *(const float4*)(w2 + widx + 4);
  float4 sa = *(const float4*)(svec + b * 1536 + i);
  float4 sb = *(const float4*)(svec + b * 1536 + i + 4);
  uint4 o;
  o.x = (u32)f2bf(wa.x * sa.x) | ((u32)f2bf(wa.y * sa.y) << 16);
  o.y = (u32)f2bf(wa.z * sa.z) | ((u32)f2bf(wa.w * sa.w) << 16);
  o.z = (u32)f2bf(wb.x * sb.x) | ((u32)f2bf(wb.y * sb.y) << 16);
  o.w = (u32)f2bf(wb.z * sb.z) | ((u32)f2bf(wb.w * sb.w) << 16);
  *(uint4*)(out + e0) = o;
}

// ---------------------------------------------------------------------------
// m97-regime 128x128 K-loop: 256 thr (4 waves, 2Mx2N), BK=64, single 32KB
// buffer, 2-phase syncthreads loop, gld16 both panels, XOR-swizzled LDS
// (pre-swizzled global source + swizzled ds_read; verified 0 conflicts in R5).
// ~3 blocks/CU resident: cross-block TLP hides prologue/drain/epilogue.
// Per-wave output 64x64: acc[4][4] fragments of 16x16, 64 f32 regs.
template<int KD>
__device__ __forceinline__ void gemm_kloop(const u16* __restrict__ Ag,
                                           const u16* __restrict__ Bg,
                                           u16* lds, int NT,
                                           f32x4_t (&acc)[4][4]) {
  const int tid = threadIdx.x;
  const int l = tid & 63, l15 = l & 15, lq = l >> 4;
  const int w = tid >> 6;                         // 0..3
  const int wm = w >> 1, wn = w & 1;
  const int rin = tid >> 3;                       // 0..31
  const int cs = ((tid & 7) ^ (rin & 7)) << 3;    // pre-swizzled k-chunk (u16)
  u16* lA = lds;                                   // [128][64] u16
  u16* lB = lds + 8192;                            // [128][64] u16

  for (int S = 0; S < NT; ++S) {
    const int kt = S * 64;
    #pragma unroll
    for (int c = 0; c < 4; ++c) {
      gld16(Ag + (size_t)(c * 32 + rin) * KD + kt + cs, lA + (c * 32 + w * 8) * 64);
      gld16(Bg + (size_t)(c * 32 + rin) * KD + kt + cs, lB + (c * 32 + w * 8) * 64);
    }
    __syncthreads();   // drains vmcnt(0): staged tile visible to all waves
    bf16x8_t af[4][2], bf[4][2];
    #pragma unroll
    for (int f = 0; f < 4; ++f) {
      const int Ra = wm * 64 + f * 16 + l15;
      const int Rb = wn * 64 + f * 16 + l15;
      #pragma unroll
      for (int kk = 0; kk < 2; ++kk) {
        af[f][kk] = *(const bf16x8_t*)(lA + Ra * 64 + (((kk * 4 + lq) ^ (Ra & 7)) << 3));
        bf[f][kk] = *(const bf16x8_t*)(lB + Rb * 64 + (((kk * 4 + lq) ^ (Rb & 7)) << 3));
      }
    }
    #pragma unroll
    for (int i = 0; i < 4; ++i)
      #pragma unroll
      for (int j = 0; j < 4; ++j)
        #pragma unroll
        for (int kk = 0; kk < 2; ++kk)
          acc[i][j] = __builtin_amdgcn_mfma_f32_16x16x32_bf16(af[i][kk], bf[j][kk], acc[i][j], 0, 0, 0);
    __syncthreads();   // all reads done before next stage overwrites
  }
}

// ---------------------------------------------------------------------------
// GEMM1: h = gelu(y_ln . w1^T + b1), M=32768 K=512 N=1536; + gsum col sumsq
__global__ __launch_bounds__(256) void gemm1_kernel(const u16* __restrict__ A,
                                                    const u16* __restrict__ Bw,
                                                    const float* __restrict__ b1,
                                                    u16* __restrict__ H,
                                                    float* __restrict__ gsum) {
  __shared__ __align__(16) u16 smem[16640];   // K-loop 16384 u16; epi stage 128x130
  const int tid = threadIdx.x;
  const int l = tid & 63, l15 = l & 15, lq = l >> 4;
  const int w = tid >> 6, wm = w >> 1, wn = w & 1;
  const int wg = swz8(blockIdx.x, 3072);
  const int ntile = wg % 12, mtile = wg / 12;   // consecutive wg share A-panel
  const int m0 = mtile * 128, n0 = ntile * 128;
  const int bidx = m0 >> 11;

  f32x4_t acc[4][4];
  #pragma unroll
  for (int i = 0; i < 4; ++i)
    #pragma unroll
    for (int j = 0; j < 4; ++j) {
      f32x4_t z = {0.f, 0.f, 0.f, 0.f};
      acc[i][j] = z;
    }

  gemm_kloop<512>(A + (size_t)m0 * 512, Bw + (size_t)n0 * 512, smem, 8, acc);

  float bj[4];
  #pragma unroll
  for (int nf = 0; nf < 4; ++nf) bj[nf] = b1[n0 + wn * 64 + nf * 16 + l15];

  float ss[4] = {0.f, 0.f, 0.f, 0.f};
  #pragma unroll
  for (int mf = 0; mf < 4; ++mf) {
    const int lr = wm * 64 + mf * 16 + lq * 4;
    #pragma unroll
    for (int nf = 0; nf < 4; ++nf) {
      const int cl = wn * 64 + nf * 16 + l15;
      #pragma unroll
      for (int r = 0; r < 4; ++r) {
        float g = gelu_f(acc[mf][nf][r] + bj[nf]);
        ss[nf] += g * g;
        smem[(lr + r) * 130 + cl] = f2bf(g);
      }
    }
  }
  #pragma unroll
  for (int nf = 0; nf < 4; ++nf) {
    float v = ss[nf];
    v += __shfl_xor(v, 16);
    v += __shfl_xor(v, 32);
    if (lq == 0) atomicAdd(&gsum[bidx * 1536 + n0 + wn * 64 + nf * 16 + l15], v);
  }
  __syncthreads();
  #pragma unroll
  for (int it = 0; it < 8; ++it) {
    int idx = it * 256 + tid;      // 0..2047 = 128 rows x 16 chunks
    int row = idx >> 4, ch = idx & 15;
    uint4 v = *(const uint4*)(smem + row * 130 + ch * 8);
    *(uint4*)(H + (size_t)(m0 + row) * 1536 + n0 + ch * 8) = v;
  }
}

// ---------------------------------------------------------------------------
// GEMM2: out[b][c][t] = x + h . w2s(b)^T + b2ob[c], M=32768 K=1536 N=512
__global__ __launch_bounds__(256) void gemm2_kernel(const u16* __restrict__ Hm,
                                                    const u16* __restrict__ W2s,
                                                    const float* __restrict__ b2ob,
                                                    const float* __restrict__ X,
                                                    float* __restrict__ Out) {
  __shared__ __align__(16) u16 smem[16640];   // K-loop 32KB; epi stage [64][129] f32
  const int tid = threadIdx.x;
  const int l = tid & 63, l15 = l & 15, lq = l >> 4;
  const int w = tid >> 6, wm = w >> 1, wn = w & 1;
  const int wg = swz8(blockIdx.x, 1024);
  const int ntile = wg & 3, mtile = wg >> 2;
  const int m0 = mtile * 128, n0 = ntile * 128;
  const int bidx = m0 >> 11, t0 = m0 & 2047;

  f32x4_t acc[4][4];
  #pragma unroll
  for (int i = 0; i < 4; ++i)
    #pragma unroll
    for (int j = 0; j < 4; ++j) {
      f32x4_t z = {0.f, 0.f, 0.f, 0.f};
      acc[i][j] = z;
    }

  gemm_kloop<1536>(Hm + (size_t)m0 * 1536,
                   W2s + ((size_t)bidx * 512 + n0) * 1536, smem, 24, acc);

  // transpose epilogue: 2 halves of 64 t-rows; f32 stage [64][129] conflict-free
  float* st = (float*)smem;
  for (int half = 0; half < 2; ++half) {
    __syncthreads();
    if (wm == half) {
      #pragma unroll
      for (int mf = 0; mf < 4; ++mf) {
        const int lr = mf * 16 + lq * 4;
        #pragma unroll
        for (int nf = 0; nf < 4; ++nf) {
          const int cl = wn * 64 + nf * 16 + l15;
          #pragma unroll
          for (int r = 0; r < 4; ++r)
            st[(lr + r) * 129 + cl] = acc[mf][nf][r];
        }
      }
    }
    __syncthreads();
    const size_t obase = ((size_t)bidx * 512 + n0) * 2048 + (size_t)(t0 + half * 64 + l);
    #pragma unroll
    for (int cc = 0; cc < 32; ++cc) {
      const int c = w * 32 + cc;
      float v = st[l * 129 + c] + b2ob[n0 + c];
      size_t oi = obase + (size_t)c * 2048;
      Out[oi] = v + X[oi];
    }
  }
}

// ---------------------------------------------------------------------------
extern "C" void kernel_launch(void* const* d_in, const int* in_sizes, int n_in,
                              void* d_out, int out_size, void* d_ws, size_t ws_size,
                              hipStream_t stream) {
  const float* x     = (const float*)d_in[0];
  const float* dw_w  = (const float*)d_in[1];
  const float* dw_b  = (const float*)d_in[2];
  const float* ln_g  = (const float*)d_in[3];
  const float* ln_b  = (const float*)d_in[4];
  const float* w1    = (const float*)d_in[5];
  const float* b1    = (const float*)d_in[6];
  const float* grn_g = (const float*)d_in[7];
  const float* grn_b = (const float*)d_in[8];
  const float* w2    = (const float*)d_in[9];
  const float* b2    = (const float*)d_in[10];
  float* out = (float*)d_out;

  // workspace layout (w2s overlays y_ln: y_ln is dead after gemm1)
  u16* y_ln = (u16*)d_ws;                             // 32768*512 u16
  u16* w2s  = y_ln;                                   // 16*512*1536 u16
  u16* h    = y_ln + (size_t)32768 * 512;             // 32768*1536 u16
  u16* w1b  = h + (size_t)32768 * 1536;               // 1536*512 u16
  float* gsum = (float*)(w1b + (size_t)1536 * 512);   // 16*1536 f32
  float* svec = gsum + 16 * 1536;                     // 16*1536 f32
  float* b2ob = svec + 16 * 1536;                     // 512 f32

  hipMemsetAsync(gsum, 0, 16 * 1536 * sizeof(float), stream);
  cast_kernel<<<768, 256, 0, stream>>>(w1, w1b, 1536 * 512);
  b2ob_kernel<<<512, 64, 0, stream>>>(w2, grn_b, b2, b2ob);
  conv_ln_kernel<<<dim3(32, 16), 512, 0, stream>>>(x, dw_w, dw_b, ln_g, ln_b, y_ln);
  gemm1_kernel<<<3072, 256, 0, stream>>>(y_ln, w1b, b1, h, gsum);
  grn_kernel<<<16, 256, 0, stream>>>(gsum, grn_g, svec);
  w2s_kernel<<<6144, 256, 0, stream>>>(w2, svec, w2s);
  gemm2_kernel<<<1024, 256, 0, stream>>>(h, w2s, b2ob, x, out);
}

// Round 7
// 227.272 us; speedup vs baseline: 1.4843x; 1.0891x over previous
//
#include <hip/hip_runtime.h>
#include <math.h>

typedef unsigned short u16;
typedef unsigned int u32;
typedef __bf16 bf16x8_t __attribute__((ext_vector_type(8)));
typedef float f32x4_t __attribute__((ext_vector_type(4)));

__device__ __forceinline__ u16 f2bf(float f) {
  __bf16 b = (__bf16)f;
  return __builtin_bit_cast(u16, b);
}

__device__ __forceinline__ void gld16(const void* g, void* l) {
  __builtin_amdgcn_global_load_lds(
      (const __attribute__((address_space(1))) void*)g,
      (__attribute__((address_space(3))) void*)l, 16, 0, 0);
}

// tanh-form GELU via rcp: gelu = v - v*rcp(e^{2z}+1). Correct limits at +/-inf.
__device__ __forceinline__ float gelu_f(float v) {
  float z = 0.7978845608028654f * v * fmaf(0.044715f, v * v, 1.0f);
  float t = __builtin_amdgcn_exp2f(2.8853900817779268f * z);   // e^{2z}
  float r = __builtin_amdgcn_rcpf(t + 1.0f);
  return v - v * r;
}

__device__ __forceinline__ int swz8(int bid, int nwg) {
  int cpx = nwg >> 3;                 // requires nwg % 8 == 0
  return (bid & 7) * cpx + (bid >> 3);
}

// ---------------------------------------------------------------------------
// cast fp32 -> bf16 (w1)
__global__ __launch_bounds__(256) void cast_kernel(const float* __restrict__ src,
                                                   u16* __restrict__ dst, int n) {
  int i = (blockIdx.x * 256 + threadIdx.x) * 4;
  if (i < n) {
    float4 v = *(const float4*)(src + i);
    uint2 o;
    o.x = (u32)f2bf(v.x) | ((u32)f2bf(v.y) << 16);
    o.y = (u32)f2bf(v.z) | ((u32)f2bf(v.w) << 16);
    *(uint2*)(dst + i) = o;
  }
}

// ---------------------------------------------------------------------------
// b2ob[c] = b2[c] + sum_i grn_b[i]*w2[c][i]
__global__ __launch_bounds__(64) void b2ob_kernel(const float* __restrict__ w2,
                                                  const float* __restrict__ grn_b,
                                                  const float* __restrict__ b2,
                                                  float* __restrict__ out) {
  int c = blockIdx.x;
  int l = threadIdx.x;
  float p = 0.f;
  for (int i = l; i < 1536; i += 64) p += grn_b[i] * w2[(size_t)c * 1536 + i];
  #pragma unroll
  for (int s = 32; s; s >>= 1) p += __shfl_xor(p, s);
  if (l == 0) out[c] = b2[c] + p;
}

// ---------------------------------------------------------------------------
// depthwise conv (K=7, pad 3) + LayerNorm over C, output bf16 [B*T][512]
__global__ __launch_bounds__(512, 4) void conv_ln_kernel(const float* __restrict__ X,
                                                         const float* __restrict__ Wd,
                                                         const float* __restrict__ bd,
                                                         const float* __restrict__ lng,
                                                         const float* __restrict__ lnb,
                                                         u16* __restrict__ Y) {
  __shared__ float ystage[16 * 516];
  __shared__ float mu_s[16], rs_s[16];

  const int c = threadIdx.x;
  const int b = blockIdx.y;
  const int t0 = blockIdx.x * 64;

  const float* xr = X + ((size_t)b * 512 + c) * 2048;
  float wr[7];
  #pragma unroll
  for (int k = 0; k < 7; ++k) wr[k] = Wd[c * 7 + k];
  const float bdv = bd[c];
  const float lg = lng[c];
  const float lb = lnb[c];

  for (int ch = 0; ch < 4; ++ch) {
    const int tc0 = t0 + ch * 16;
    const int g = tc0 - 4;
    float w[24];
    if (g >= 0 && g + 24 <= 2048) {
      #pragma unroll
      for (int q = 0; q < 6; ++q) {
        float4 v = *(const float4*)(xr + g + q * 4);
        w[q * 4 + 0] = v.x; w[q * 4 + 1] = v.y;
        w[q * 4 + 2] = v.z; w[q * 4 + 3] = v.w;
      }
    } else {
      #pragma unroll
      for (int j = 0; j < 24; ++j) {
        int tt = g + j;
        w[j] = (tt >= 0 && tt < 2048) ? xr[tt] : 0.f;
      }
    }
    float outv[16];
    #pragma unroll
    for (int i = 0; i < 16; ++i) {
      float a = bdv;
      #pragma unroll
      for (int k = 0; k < 7; ++k) a = fmaf(w[i + 1 + k], wr[k], a);
      outv[i] = a;
      ystage[i * 516 + c] = a;
    }
    __syncthreads();
    {
      int r = c >> 5, cl = c & 31;
      float s = 0.f, q = 0.f;
      #pragma unroll
      for (int k = 0; k < 16; ++k) {
        float v = ystage[r * 516 + cl + k * 32];
        s += v; q += v * v;
      }
      #pragma unroll
      for (int m = 16; m; m >>= 1) { s += __shfl_xor(s, m); q += __shfl_xor(q, m); }
      if (cl == 0) {
        float mu = s * (1.f / 512.f);
        float var = q * (1.f / 512.f) - mu * mu;
        mu_s[r] = mu;
        rs_s[r] = rsqrtf(var + 1e-6f);
      }
    }
    __syncthreads();
    #pragma unroll
    for (int i = 0; i < 16; ++i) {
      float v = (outv[i] - mu_s[i]) * rs_s[i] * lg + lb;
      Y[(size_t)(b * 2048 + tc0 + i) * 512 + c] = f2bf(v);
    }
  }
}

// ---------------------------------------------------------------------------
// GRN scale: s[b][i] = 1 + grn_g[i]*gx/(mean(gx)+1e-6)
__global__ __launch_bounds__(256) void grn_kernel(const float* __restrict__ gsum,
                                                  const float* __restrict__ grn_g,
                                                  float* __restrict__ svec) {
  __shared__ float red[256];
  int b = blockIdx.x, tid = threadIdx.x;
  float gx[6];
  float part = 0.f;
  #pragma unroll
  for (int it = 0; it < 6; ++it) {
    int i = it * 256 + tid;
    gx[it] = sqrtf(gsum[b * 1536 + i]);
    part += gx[it];
  }
  red[tid] = part;
  __syncthreads();
  for (int s = 128; s; s >>= 1) {
    if (tid < s) red[tid] += red[tid + s];
    __syncthreads();
  }
  float inv = 1.0f / (red[0] * (1.f / 1536.f) + 1e-6f);
  #pragma unroll
  for (int it = 0; it < 6; ++it) {
    int i = it * 256 + tid;
    svec[b * 1536 + i] = 1.0f + grn_g[i] * gx[it] * inv;
  }
}

// ---------------------------------------------------------------------------
// w2s[b][c][i] = bf16( w2[c][i] * svec[b][i] )
__global__ __launch_bounds__(256) void w2s_kernel(const float* __restrict__ w2,
                                                  const float* __restrict__ svec,
                                                  u16* __restrict__ out) {
  size_t e0 = ((size_t)blockIdx.x * 256 + threadIdx.x) * 8;  // flat into [16][512][1536]
  int i = (int)(e0 % 1536);
  size_t bc = e0 / 1536;
  int b = (int)(bc >> 9);
  size_t widx = (bc & 511) * 1536 + i;
  float4 wa = *(const float4*)(w2 + widx);
  float4 wb = *(const float4*)(w2 + widx + 4);
  float4 sa = *(const float4*)(svec + b * 1536 + i);
  float4 sb = *(const float4*)(svec + b * 1536 + i + 4);
  uint4 o;
  o.x = (u32)f2bf(wa.x * sa.x) | ((u32)f2bf(wa.y * sa.y) << 16);
  o.y = (u32)f2bf(wa.z * sa.z) | ((u32)f2bf(wa.w * sa.w) << 16);
  o.z = (u32)f2bf(wb.x * sb.x) | ((u32)f2bf(wb.y * sb.y) << 16);
  o.w = (u32)f2bf(wb.z * sb.z) | ((u32)f2bf(wb.w * sb.w) << 16);
  *(uint4*)(out + e0) = o;
}

// ---------------------------------------------------------------------------
// 128x128-tile K-loop, T3-minimum 2-phase double-buffered pipeline:
//   prologue: STAGE(buf0, t=0); syncthreads (drains vmcnt)
//   loop t:   STAGE(buf^1, t+1)   <- issued BEFORE compute
//             ds_read buf[cur]; MFMA
//             syncthreads         <- compiler's vmcnt(0) drain lands here,
//                                    AFTER the compute window hid the latency
// Race-safety: one barrier/step suffices — every wave's buf[cur] ds_reads
// complete (into regs) before its MFMAs, hence before it reaches the barrier;
// the overwriting STAGE of buf[cur] is only issued after that barrier.
// LDS: 2 buffers x (A[128][64] + B[128][64]) u16 = 64KB -> 2 blocks/CU.
// XOR-swizzled (pre-swizzled global source + swizzled ds_read; 0 conflicts, R5).
template<int KD>
__device__ __forceinline__ void gemm_kloop(const u16* __restrict__ Ag,
                                           const u16* __restrict__ Bg,
                                           u16* lds, int NT,
                                           f32x4_t (&acc)[4][4]) {
  const int tid = threadIdx.x;
  const int l = tid & 63, l15 = l & 15, lq = l >> 4;
  const int w = tid >> 6;                         // 0..3
  const int wm = w >> 1, wn = w & 1;
  const int rin = tid >> 3;                       // 0..31
  const int cs = ((tid & 7) ^ (rin & 7)) << 3;    // pre-swizzled k-chunk (u16)

  auto STAGE = [&](int buf, int kt) {
    u16* lA = lds + buf * 16384;
    u16* lB = lA + 8192;
    #pragma unroll
    for (int c = 0; c < 4; ++c) {
      gld16(Ag + (size_t)(c * 32 + rin) * KD + kt + cs, lA + (c * 32 + w * 8) * 64);
      gld16(Bg + (size_t)(c * 32 + rin) * KD + kt + cs, lB + (c * 32 + w * 8) * 64);
    }
  };

  STAGE(0, 0);
  __syncthreads();

  for (int S = 0; S < NT; ++S) {
    const int cur = S & 1;
    if (S + 1 < NT) STAGE(cur ^ 1, (S + 1) * 64);   // prefetch next tile
    u16* lA = lds + cur * 16384;
    u16* lB = lA + 8192;
    bf16x8_t af[4][2], bf[4][2];
    #pragma unroll
    for (int f = 0; f < 4; ++f) {
      const int Ra = wm * 64 + f * 16 + l15;
      const int Rb = wn * 64 + f * 16 + l15;
      #pragma unroll
      for (int kk = 0; kk < 2; ++kk) {
        af[f][kk] = *(const bf16x8_t*)(lA + Ra * 64 + (((kk * 4 + lq) ^ (Ra & 7)) << 3));
        bf[f][kk] = *(const bf16x8_t*)(lB + Rb * 64 + (((kk * 4 + lq) ^ (Rb & 7)) << 3));
      }
    }
    #pragma unroll
    for (int i = 0; i < 4; ++i)
      #pragma unroll
      for (int j = 0; j < 4; ++j)
        #pragma unroll
        for (int kk = 0; kk < 2; ++kk)
          acc[i][j] = __builtin_amdgcn_mfma_f32_16x16x32_bf16(af[i][kk], bf[j][kk], acc[i][j], 0, 0, 0);
    __syncthreads();   // drains prefetch vmcnt AFTER compute; protects buffer swap
  }
}

// ---------------------------------------------------------------------------
// GEMM1: h = gelu(y_ln . w1^T + b1), M=32768 K=512 N=1536; + gsum col sumsq
__global__ __launch_bounds__(256) void gemm1_kernel(const u16* __restrict__ A,
                                                    const u16* __restrict__ Bw,
                                                    const float* __restrict__ b1,
                                                    u16* __restrict__ H,
                                                    float* __restrict__ gsum) {
  extern __shared__ __align__(16) u16 lds[];   // 64KB kloop; epi overlays 128x130 u16
  const int tid = threadIdx.x;
  const int l = tid & 63, l15 = l & 15, lq = l >> 4;
  const int w = tid >> 6, wm = w >> 1, wn = w & 1;
  const int wg = swz8(blockIdx.x, 3072);
  const int ntile = wg % 12, mtile = wg / 12;   // consecutive wg share A-panel
  const int m0 = mtile * 128, n0 = ntile * 128;
  const int bidx = m0 >> 11;

  f32x4_t acc[4][4];
  #pragma unroll
  for (int i = 0; i < 4; ++i)
    #pragma unroll
    for (int j = 0; j < 4; ++j) {
      f32x4_t z = {0.f, 0.f, 0.f, 0.f};
      acc[i][j] = z;
    }

  gemm_kloop<512>(A + (size_t)m0 * 512, Bw + (size_t)n0 * 512, lds, 8, acc);

  float bj[4];
  #pragma unroll
  for (int nf = 0; nf < 4; ++nf) bj[nf] = b1[n0 + wn * 64 + nf * 16 + l15];

  float ss[4] = {0.f, 0.f, 0.f, 0.f};
  #pragma unroll
  for (int mf = 0; mf < 4; ++mf) {
    const int lr = wm * 64 + mf * 16 + lq * 4;
    #pragma unroll
    for (int nf = 0; nf < 4; ++nf) {
      const int cl = wn * 64 + nf * 16 + l15;
      #pragma unroll
      for (int r = 0; r < 4; ++r) {
        float g = gelu_f(acc[mf][nf][r] + bj[nf]);
        ss[nf] += g * g;
        lds[(lr + r) * 130 + cl] = f2bf(g);
      }
    }
  }
  #pragma unroll
  for (int nf = 0; nf < 4; ++nf) {
    float v = ss[nf];
    v += __shfl_xor(v, 16);
    v += __shfl_xor(v, 32);
    if (lq == 0) atomicAdd(&gsum[bidx * 1536 + n0 + wn * 64 + nf * 16 + l15], v);
  }
  __syncthreads();
  #pragma unroll
  for (int it = 0; it < 8; ++it) {
    int idx = it * 256 + tid;      // 0..2047 = 128 rows x 16 chunks
    int row = idx >> 4, ch = idx & 15;
    uint4 v = *(const uint4*)(lds + row * 130 + ch * 8);
    *(uint4*)(H + (size_t)(m0 + row) * 1536 + n0 + ch * 8) = v;
  }
}

// ---------------------------------------------------------------------------
// GEMM2: out[b][c][t] = x + h . w2s(b)^T + b2ob[c], M=32768 K=1536 N=512
__global__ __launch_bounds__(256) void gemm2_kernel(const u16* __restrict__ Hm,
                                                    const u16* __restrict__ W2s,
                                                    const float* __restrict__ b2ob,
                                                    const float* __restrict__ X,
                                                    float* __restrict__ Out) {
  extern __shared__ __align__(16) u16 lds[];   // 64KB kloop; epi overlays [64][129] f32
  const int tid = threadIdx.x;
  const int l = tid & 63, l15 = l & 15, lq = l >> 4;
  const int w = tid >> 6, wm = w >> 1, wn = w & 1;
  const int wg = swz8(blockIdx.x, 1024);
  const int ntile = wg & 3, mtile = wg >> 2;
  const int m0 = mtile * 128, n0 = ntile * 128;
  const int bidx = m0 >> 11, t0 = m0 & 2047;

  f32x4_t acc[4][4];
  #pragma unroll
  for (int i = 0; i < 4; ++i)
    #pragma unroll
    for (int j = 0; j < 4; ++j) {
      f32x4_t z = {0.f, 0.f, 0.f, 0.f};
      acc[i][j] = z;
    }

  gemm_kloop<1536>(Hm + (size_t)m0 * 1536,
                   W2s + ((size_t)bidx * 512 + n0) * 1536, lds, 24, acc);

  // transpose epilogue: 2 halves of 64 t-rows; f32 stage [64][129] conflict-free
  float* st = (float*)lds;
  for (int half = 0; half < 2; ++half) {
    __syncthreads();
    if (wm == half) {
      #pragma unroll
      for (int mf = 0; mf < 4; ++mf) {
        const int lr = mf * 16 + lq * 4;
        #pragma unroll
        for (int nf = 0; nf < 4; ++nf) {
          const int cl = wn * 64 + nf * 16 + l15;
          #pragma unroll
          for (int r = 0; r < 4; ++r)
            st[(lr + r) * 129 + cl] = acc[mf][nf][r];
        }
      }
    }
    __syncthreads();
    const size_t obase = ((size_t)bidx * 512 + n0) * 2048 + (size_t)(t0 + half * 64 + l);
    #pragma unroll
    for (int cc = 0; cc < 32; ++cc) {
      const int c = w * 32 + cc;
      float v = st[l * 129 + c] + b2ob[n0 + c];
      size_t oi = obase + (size_t)c * 2048;
      Out[oi] = v + X[oi];
    }
  }
}

// ---------------------------------------------------------------------------
extern "C" void kernel_launch(void* const* d_in, const int* in_sizes, int n_in,
                              void* d_out, int out_size, void* d_ws, size_t ws_size,
                              hipStream_t stream) {
  const float* x     = (const float*)d_in[0];
  const float* dw_w  = (const float*)d_in[1];
  const float* dw_b  = (const float*)d_in[2];
  const float* ln_g  = (const float*)d_in[3];
  const float* ln_b  = (const float*)d_in[4];
  const float* w1    = (const float*)d_in[5];
  const float* b1    = (const float*)d_in[6];
  const float* grn_g = (const float*)d_in[7];
  const float* grn_b = (const float*)d_in[8];
  const float* w2    = (const float*)d_in[9];
  const float* b2    = (const float*)d_in[10];
  float* out = (float*)d_out;

  // workspace layout (w2s overlays y_ln: y_ln is dead after gemm1)
  u16* y_ln = (u16*)d_ws;                             // 32768*512 u16
  u16* w2s  = y_ln;                                   // 16*512*1536 u16
  u16* h    = y_ln + (size_t)32768 * 512;             // 32768*1536 u16
  u16* w1b  = h + (size_t)32768 * 1536;               // 1536*512 u16
  float* gsum = (float*)(w1b + (size_t)1536 * 512);   // 16*1536 f32
  float* svec = gsum + 16 * 1536;                     // 16*1536 f32
  float* b2ob = svec + 16 * 1536;                     // 512 f32

  (void)hipFuncSetAttribute((const void*)gemm1_kernel,
                            hipFuncAttributeMaxDynamicSharedMemorySize, 65536);
  (void)hipFuncSetAttribute((const void*)gemm2_kernel,
                            hipFuncAttributeMaxDynamicSharedMemorySize, 65536);

  hipMemsetAsync(gsum, 0, 16 * 1536 * sizeof(float), stream);
  cast_kernel<<<768, 256, 0, stream>>>(w1, w1b, 1536 * 512);
  b2ob_kernel<<<512, 64, 0, stream>>>(w2, grn_b, b2, b2ob);
  conv_ln_kernel<<<dim3(32, 16), 512, 0, stream>>>(x, dw_w, dw_b, ln_g, ln_b, y_ln);
  gemm1_kernel<<<3072, 256, 65536, stream>>>(y_ln, w1b, b1, h, gsum);
  grn_kernel<<<16, 256, 0, stream>>>(gsum, grn_g, svec);
  w2s_kernel<<<6144, 256, 0, stream>>>(w2, svec, w2s);
  gemm2_kernel<<<1024, 256, 65536, stream>>>(h, w2s, b2ob, x, out);
}